// Round 6
// baseline (1712.009 us; speedup 1.0000x reference)
//
#include <hip/hip_runtime.h>
#include <hip/hip_fp16.h>
#include <math.h>

// MIPNetwork: 3-pass GNN. F=64. Round 6: LDS-free per-wave MFMA GEMMs
// (A-frags loaded straight from global f32 -> f16 in regs; B-frags from
// pre-transposed f16 WT[C][K], L1-resident; no barriers, no LDS).
// build_all_k list appends use nontemporal stores.

constexpr int VAR_N = 50000;
constexpr int CON_N = 50000;
constexpr int EQ_N  = 10000;
constexpr int NNZ_I = 800000;
constexpr int NNZ_E = 200000;
constexpr int NPASS = 3;

constexpr int CAP_ID = 48;
constexpr int CAP_IS = 48;
constexpr int CAP_ED = 64;
constexpr int CAP_ES = 24;

typedef _Float16 f16x8 __attribute__((ext_vector_type(8)));
typedef float    f32x4 __attribute__((ext_vector_type(4)));

__device__ __forceinline__ float wred(float v) {
#pragma unroll
  for (int o = 32; o > 0; o >>= 1) v += __shfl_down(v, o, 64);
  return v;
}

__device__ __forceinline__ float unpack_val(unsigned e) {
  return __half2float(__ushort_as_half((unsigned short)(e & 0xFFFFu)));
}

// ---------------- weight prep: f32 [K][C] -> f16 transposed [C][K] ----------------
struct PrepArgs {
  const float* src[9];
  int K[9]; int C[9]; int base[9]; int end[9];
};

__global__ __launch_bounds__(256) void prep_wt_k(PrepArgs a, __half* __restrict__ wt)
{
  int idx = blockIdx.x * 256 + threadIdx.x;
  if (idx >= 65536) return;
#pragma unroll
  for (int i = 0; i < 9; ++i) {
    if (idx < a.end[i]) {
      int local = idx - a.base[i];
      int k = local % a.K[i];
      int c = local / a.K[i];
      wt[idx] = __float2half_rn(a.src[i][(size_t)k * a.C[i] + c]);
      return;
    }
  }
}

// ---------------- MFMA GEMM (LDS-free, per-wave) ----------------
// out[N x COLS] = X[N x K] @ W + bias
// MODE 0: X = X0[N x K]; MODE 1: X = concat(X0[N x 64], X1[N x (K-64)])
// EXTRA 0: none; 1: += noise4 @ Wf32[K..K+3]; 2: += (obj*oscale, mask) @ Wf32[K..K+1]
// RELUNORM: X' = relu(X) * rsqrt(1e-6 + (*ssin)/ssdiv)
// OUT_SS: atomicAdd(ssout, sum(out^2))
// POSTOP 0: out=v; 1: out=v+0.5*aux[row]; 2: out=v+0.5*aux[row*64+col];
//        3: col<64: aux[row*64+col]=v+0.5*aux; col>=64: out[row*64+col-64]=v
struct GemmSide {
  const float* X0; const float* X1;
  const __half* WT;                     // f16 transposed [COLS][K]
  const float* W;  const float* bias;   // f32 originals (epilogue extras)
  float* out; float* aux;
  const float* ssin; float* ssout; float ssdiv;
  const float* exA; const float* exB; const float* exScale;
  int N; int nblk;
};

template<int K, int COLS, int MODE, int EXTRA, bool RELUNORM, bool OUT_SS, int POSTOP>
__global__ __launch_bounds__(256) void mlp_gemm(GemmSide A, GemmSide B)
{
  constexpr int NCB = COLS / 16;

  const bool inA = (blockIdx.x < (unsigned)A.nblk);
  const GemmSide& S = inA ? A : B;
  const int bid = blockIdx.x - (inA ? 0 : A.nblk);

  const int tid = threadIdx.x, lane = tid & 63, wid = tid >> 6;
  const int rowW = bid * 64 + wid * 16;      // wave's 16-row strip
  if (rowW >= S.N) return;
  const int arow = rowW + (lane & 15);       // row this lane feeds into A-frag
  const int kgrp = (lane >> 4) * 8;          // k-offset within 32-step
  const bool rok = arow < S.N;

  float inv_s = 1.0f;
  if constexpr (RELUNORM) inv_s = rsqrtf(1e-6f + (*S.ssin) / S.ssdiv);

  f32x4 acc[NCB] = {};

  for (int k0 = 0; k0 < K; k0 += 32) {
    const int gk = k0 + kgrp;
    f16x8 af = { (_Float16)0, (_Float16)0, (_Float16)0, (_Float16)0,
                 (_Float16)0, (_Float16)0, (_Float16)0, (_Float16)0 };
    if (rok) {
      const float* p;
      if constexpr (MODE == 0) p = S.X0 + (size_t)arow * K + gk;
      else p = (gk < 64) ? (S.X0 + ((size_t)arow << 6) + gk)
                         : (S.X1 + (size_t)arow * (K - 64) + (gk - 64));
      float4 u = *(const float4*)p;
      float4 v = *(const float4*)(p + 4);
      if constexpr (RELUNORM) {
        u.x = fmaxf(u.x, 0.0f) * inv_s; u.y = fmaxf(u.y, 0.0f) * inv_s;
        u.z = fmaxf(u.z, 0.0f) * inv_s; u.w = fmaxf(u.w, 0.0f) * inv_s;
        v.x = fmaxf(v.x, 0.0f) * inv_s; v.y = fmaxf(v.y, 0.0f) * inv_s;
        v.z = fmaxf(v.z, 0.0f) * inv_s; v.w = fmaxf(v.w, 0.0f) * inv_s;
      }
      af[0] = (_Float16)u.x; af[1] = (_Float16)u.y;
      af[2] = (_Float16)u.z; af[3] = (_Float16)u.w;
      af[4] = (_Float16)v.x; af[5] = (_Float16)v.y;
      af[6] = (_Float16)v.z; af[7] = (_Float16)v.w;
    }
#pragma unroll
    for (int c = 0; c < NCB; ++c) {
      const f16x8 bf = *(const f16x8*)(S.WT + (size_t)(c * 16 + (lane & 15)) * K + gk);
      acc[c] = __builtin_amdgcn_mfma_f32_16x16x32_f16(af, bf, acc[c], 0, 0, 0);
    }
  }

  // ---------------- epilogue (f32) ----------------
  float ssloc = 0.0f;
  float bcol[NCB], ew0[NCB], ew1[NCB], ew2[NCB], ew3[NCB];
#pragma unroll
  for (int c = 0; c < NCB; ++c) {
    int col = c * 16 + (lane & 15);
    bcol[c] = S.bias[col];
    if constexpr (EXTRA == 1) {
      ew0[c] = S.W[(size_t)(K + 0) * COLS + col];
      ew1[c] = S.W[(size_t)(K + 1) * COLS + col];
      ew2[c] = S.W[(size_t)(K + 2) * COLS + col];
      ew3[c] = S.W[(size_t)(K + 3) * COLS + col];
    }
    if constexpr (EXTRA == 2) {
      ew0[c] = S.W[(size_t)(K + 0) * COLS + col];
      ew1[c] = S.W[(size_t)(K + 1) * COLS + col];
    }
  }
  float oscale = 0.0f;
  if constexpr (EXTRA == 2) oscale = 1.0f / (sqrtf((*S.exScale) * (1.0f / VAR_N)) + 1e-6f);

#pragma unroll
  for (int j = 0; j < 4; ++j) {
    int grow = rowW + ((lane >> 4) << 2) + j;
    if (grow < S.N) {
      float nx = 0, ny = 0, nz = 0, nw = 0, ov = 0, mv = 0;
      if constexpr (EXTRA == 1) {
        float4 n4 = *reinterpret_cast<const float4*>(&S.exA[(size_t)grow * 4]);
        nx = n4.x; ny = n4.y; nz = n4.z; nw = n4.w;
      }
      if constexpr (EXTRA == 2) { ov = S.exA[grow] * oscale; mv = S.exB[grow]; }
#pragma unroll
      for (int c = 0; c < NCB; ++c) {
        int col = c * 16 + (lane & 15);
        float v = acc[c][j] + bcol[c];
        if constexpr (EXTRA == 1)
          v = fmaf(nx, ew0[c], fmaf(ny, ew1[c], fmaf(nz, ew2[c], fmaf(nw, ew3[c], v))));
        if constexpr (EXTRA == 2)
          v = fmaf(ov, ew0[c], fmaf(mv, ew1[c], v));
        if constexpr (POSTOP == 1) v += 0.5f * S.aux[grow];
        if constexpr (POSTOP == 2) v += 0.5f * S.aux[((size_t)grow << 6) + col];
        if constexpr (POSTOP == 3) {
          if (col < 64) {
            float nv = v + 0.5f * S.aux[((size_t)grow << 6) + col];
            S.aux[((size_t)grow << 6) + col] = nv;
          } else {
            S.out[((size_t)grow << 6) + (col - 64)] = v;
          }
        } else {
          S.out[(size_t)grow * COLS + col] = v;
        }
        if constexpr (OUT_SS) ssloc = fmaf(v, v, ssloc);
      }
    }
  }
  if constexpr (OUT_SS) {
    ssloc = wred(ssloc);
    if (lane == 0) atomicAdd(S.ssout, ssloc);
  }
}

// ---------------- adjacency build: packed-list append, nontemporal stores ----------------
__global__ __launch_bounds__(256) void build_all_k(
    const int* __restrict__ isrc, const int* __restrict__ idst, const float* __restrict__ ival,
    const int* __restrict__ esrc, const int* __restrict__ edst, const float* __restrict__ evalv,
    int* __restrict__ cntID, unsigned* __restrict__ listID,
    int* __restrict__ cntIS, unsigned* __restrict__ listIS,
    int* __restrict__ cntED, unsigned* __restrict__ listED,
    int* __restrict__ cntES, unsigned* __restrict__ listES)
{
  int gid = blockIdx.x * 256 + threadIdx.x;
  if (gid < NNZ_I) {
    int s = isrc[gid], d = idst[gid];
    unsigned hb = (unsigned)__half_as_ushort(__float2half_rn(ival[gid]));
    int pd = atomicAdd(&cntID[d], 1);
    if (pd < CAP_ID) __builtin_nontemporal_store(((unsigned)s << 16) | hb,
                                                 &listID[(size_t)d * CAP_ID + pd]);
    int ps = atomicAdd(&cntIS[s], 1);
    if (ps < CAP_IS) __builtin_nontemporal_store(((unsigned)d << 16) | hb,
                                                 &listIS[(size_t)s * CAP_IS + ps]);
  } else if (gid < NNZ_I + NNZ_E) {
    int e = gid - NNZ_I;
    int s = esrc[e], d = edst[e];
    unsigned hb = (unsigned)__half_as_ushort(__float2half_rn(evalv[e]));
    int pd = atomicAdd(&cntED[d], 1);
    if (pd < CAP_ED) __builtin_nontemporal_store(((unsigned)s << 16) | hb,
                                                 &listED[(size_t)d * CAP_ED + pd]);
    int ps = atomicAdd(&cntES[s], 1);
    if (ps < CAP_ES) __builtin_nontemporal_store(((unsigned)d << 16) | hb,
                                                 &listES[(size_t)s * CAP_ES + ps]);
  }
}

// ---------------- state init: one wave per row ----------------
__global__ __launch_bounds__(256) void init_rows_k(
    const float* __restrict__ relaxed,
    const int* __restrict__ cntID, const unsigned* __restrict__ listID,
    const int* __restrict__ cntED, const unsigned* __restrict__ listED,
    float* __restrict__ variables, float* __restrict__ constraints, float* __restrict__ eqcons)
{
  int widx = blockIdx.x * 4 + (threadIdx.x >> 6);
  int lane = threadIdx.x & 63;
  if (widx < VAR_N) {
    variables[((size_t)widx << 6) + lane] = relaxed[widx];
  } else if (widx < VAR_N + CON_N) {
    int i = widx - VAR_N;
    int n = min(cntID[i], CAP_ID);
    float t = 0.0f;
    if (lane < n) {
      unsigned e = listID[(size_t)i * CAP_ID + lane];
      t = unpack_val(e) * relaxed[e >> 16];
    }
    t = wred(t);
    t = __shfl(t, 0, 64);
    constraints[((size_t)i << 6) + lane] = t;
  } else if (widx < VAR_N + CON_N + EQ_N) {
    int i = widx - VAR_N - CON_N;
    int n = min(cntED[i], CAP_ED);
    float t = 0.0f;
    if (lane < n) {
      unsigned e = listED[(size_t)i * CAP_ED + lane];
      t = unpack_val(e) * relaxed[e >> 16];
    }
    t = wred(t);
    t = __shfl(t, 0, 64);
    eqcons[((size_t)i << 6) + lane] = t;
  }
}

// ---------------- fused loss gathers ----------------
__global__ __launch_bounds__(256) void gather_loss_k(
    const int* __restrict__ cntC, const unsigned* __restrict__ listC,
    const int* __restrict__ cntE, const unsigned* __restrict__ listE,
    const float* __restrict__ qry,
    const float* __restrict__ cv, const float* __restrict__ ecv,
    float* __restrict__ closs, float* __restrict__ eloss)
{
  constexpr int nbC = (CON_N + 3) / 4;
  int b = blockIdx.x;
  int lane = threadIdx.x & 63;
  if (b < nbC) {
    int i = b * 4 + (threadIdx.x >> 6);
    if (i >= CON_N) return;
    int n = min(cntC[i], CAP_ID);
    const unsigned* lst = listC + (size_t)i * CAP_ID;
    float acc = 0.0f, ss = 0.0f;
    for (int j = 0; j < n; ++j) {
      unsigned e = lst[j];
      float v = unpack_val(e);
      acc = fmaf(v, qry[((size_t)(e >> 16) << 6) + lane], acc);
      ss  = fmaf(v, v, ss);
    }
    closs[((size_t)i << 6) + lane] = (acc - cv[i]) * rsqrtf(ss + 1e-6f);
  } else {
    int i = (b - nbC) * 4 + (threadIdx.x >> 6);
    if (i >= EQ_N) return;
    int n = min(cntE[i], CAP_ED);
    const unsigned* lst = listE + (size_t)i * CAP_ED;
    float acc = 0.0f, ss = 0.0f;
    for (int j = 0; j < n; ++j) {
      unsigned e = lst[j];
      float v = unpack_val(e);
      acc = fmaf(v, qry[((size_t)(e >> 16) << 6) + lane], acc);
      ss  = fmaf(v, v, ss);
    }
    float t = (ecv[i] - acc) * rsqrtf(ss + 1e-6f);
    eloss[((size_t)i << 6) + lane] = t * t;
  }
}

// ---------------- var-message gather ----------------
__global__ __launch_bounds__(256) void gather_vmsg_k(
    const int* __restrict__ cntS, const unsigned* __restrict__ listS,
    const int* __restrict__ cntES, const unsigned* __restrict__ listES,
    const float* __restrict__ ctmpHi, const float* __restrict__ etmpHi,
    float* __restrict__ msgs)
{
  int i = blockIdx.x * 4 + (threadIdx.x >> 6);
  if (i >= VAR_N) return;
  int lane = threadIdx.x & 63;

  float pos = 0.0f, neg = 0.0f, vss = 0.0f;
  {
    int n = min(cntS[i], CAP_IS);
    const unsigned* lst = listS + (size_t)i * CAP_IS;
    for (int j = 0; j < n; ++j) {
      unsigned e = lst[j];
      float v = unpack_val(e);
      float c = ctmpHi[((size_t)(e >> 16) << 6) + lane];
      vss = fmaf(v, v, vss);
      if (v > 0.0f) pos = fmaf(v, c, pos);
      else          neg = fmaf(-v, c, neg);
    }
  }
  float e2v = 0.0f;
  {
    int n = min(cntES[i], CAP_ES);
    const unsigned* lst = listES + (size_t)i * CAP_ES;
    for (int j = 0; j < n; ++j) {
      unsigned e = lst[j];
      e2v = fmaf(unpack_val(e), etmpHi[((size_t)(e >> 16) << 6) + lane], e2v);
    }
  }
  float ivs = rsqrtf(vss + 1e-6f);
  float* row = msgs + (size_t)i * 192;
  row[lane]       = pos * ivs;
  row[64 + lane]  = neg * ivs;
  row[128 + lane] = e2v;
}

// ---------------- small kernels ----------------
__global__ __launch_bounds__(256) void sumsq_k(const float* __restrict__ x, int n, float* out)
{
  float s = 0.0f;
  for (int i = blockIdx.x * 256 + threadIdx.x; i < n; i += gridDim.x * 256) {
    float v = x[i]; s = fmaf(v, v, s);
  }
  s = wred(s);
  __shared__ float red[4];
  int lane = threadIdx.x & 63, wid = threadIdx.x >> 6;
  if (lane == 0) red[wid] = s;
  __syncthreads();
  if (threadIdx.x == 0) atomicAdd(out, red[0] + red[1] + red[2] + red[3]);
}

__global__ __launch_bounds__(256) void out_k(
    const float* __restrict__ H, const float* __restrict__ ssin,
    const float* __restrict__ ow2, const float* __restrict__ ob2,
    const float* __restrict__ mask, float* __restrict__ dout, int pass)
{
  int row = blockIdx.x * 4 + (threadIdx.x >> 6);
  if (row >= VAR_N) return;
  int lane = threadIdx.x & 63;
  float inv_s = rsqrtf(1e-6f + (*ssin) / (float)VAR_N);
  float t = fmaxf(H[(size_t)row * 64 + lane] * inv_s, 0.0f) * ow2[lane];
  t = wred(t);
  if (lane == 0) {
    float ov = t + ob2[0];
    float m = mask[row];
    float sig = 1.0f / (1.0f + expf(-ov));
    dout[pass * VAR_N + row] = sig * m + ov * (1.0f - m) * 0.1f;
    if (pass == NPASS - 1) dout[3 * VAR_N + row] = ov;
  }
}

// ---------------- launch ----------------
extern "C" void kernel_launch(void* const* d_in, const int* in_sizes, int n_in,
                              void* d_out, int out_size, void* d_ws, size_t ws_size,
                              hipStream_t stream)
{
  const int*   isrc = (const int*)  d_in[0];
  const int*   idst = (const int*)  d_in[1];
  const float* ival = (const float*)d_in[2];
  const int*   esrc = (const int*)  d_in[3];
  const int*   edst = (const int*)  d_in[4];
  const float* evalv= (const float*)d_in[5];
  const float* cv   = (const float*)d_in[6];
  const float* ecv  = (const float*)d_in[7];
  const float* relaxed = (const float*)d_in[8];
  const float* obj  = (const float*)d_in[9];
  const float* mask = (const float*)d_in[10];
  const float* noise= (const float*)d_in[11];
  const float* q_w1 = (const float*)d_in[12];
  const float* q_b1 = (const float*)d_in[13];
  const float* q_w2 = (const float*)d_in[14];
  const float* q_b2 = (const float*)d_in[15];
  const float* cu_w1= (const float*)d_in[16];
  const float* cu_b1= (const float*)d_in[17];
  const float* cu_w2= (const float*)d_in[18];
  const float* cu_b2= (const float*)d_in[19];
  const float* ec_w1= (const float*)d_in[20];
  const float* ec_b1= (const float*)d_in[21];
  const float* ec_w2= (const float*)d_in[22];
  const float* ec_b2= (const float*)d_in[23];
  const float* vu_w1= (const float*)d_in[24];
  const float* vu_b1= (const float*)d_in[25];
  const float* vu_w2= (const float*)d_in[26];
  const float* vu_b2= (const float*)d_in[27];
  const float* o_w1 = (const float*)d_in[28];
  const float* o_b1 = (const float*)d_in[29];
  const float* o_w2 = (const float*)d_in[30];
  const float* o_b2 = (const float*)d_in[31];
  float* dout = (float*)d_out;
  float* w = (float*)d_ws;

  size_t off = 0;
  auto A = [&](size_t n){ size_t o = off; off += (n + 63) & ~(size_t)63; return o; };
  const size_t oVarA  = A((size_t)VAR_N * 64);
  const size_t oVarB  = A((size_t)VAR_N * 64);
  const size_t oCons  = A((size_t)CON_N * 64);
  const size_t oEqc   = A((size_t)EQ_N  * 64);
  const size_t oQry   = A((size_t)VAR_N * 64);
  const size_t oH     = A((size_t)VAR_N * 64);
  const size_t oHE    = A((size_t)EQ_N  * 64);
  const size_t oCtmp  = A((size_t)CON_N * 64);
  const size_t oEtmp  = A((size_t)EQ_N  * 64);
  const size_t oCloss = A((size_t)CON_N * 64);
  const size_t oEloss = A((size_t)EQ_N  * 64);
  const size_t oMsgs  = A((size_t)VAR_N * 192);
  const size_t oScal  = A(64);
  const size_t oWT    = A(32768);   // 65536 halves
  const size_t oCntID = A(CON_N);
  const size_t oCntIS = A(VAR_N);
  const size_t oCntED = A(EQ_N);
  const size_t oCntES = A(VAR_N);
  const size_t oListID = A((size_t)CON_N * CAP_ID);
  const size_t oListIS = A((size_t)VAR_N * CAP_IS);
  const size_t oListED = A((size_t)EQ_N  * CAP_ED);
  const size_t oListES = A((size_t)VAR_N * CAP_ES);

  float* scal = w + oScal;
  __half* wtBase = (__half*)(w + oWT);
  int*  cntID = (int*)(w + oCntID);
  int*  cntIS = (int*)(w + oCntIS);
  int*  cntED = (int*)(w + oCntED);
  int*  cntES = (int*)(w + oCntES);
  unsigned* listID = (unsigned*)(w + oListID);
  unsigned* listIS = (unsigned*)(w + oListIS);
  unsigned* listED = (unsigned*)(w + oListED);
  unsigned* listES = (unsigned*)(w + oListES);

  // WT offsets (halves), layout [C][K] per matrix
  const int bQ1 = 0,      bQ2 = 4096,  bCU1 = 8192,  bCU2 = 16384, bEC1 = 24576;
  const int bEC2 = 32768, bVU1 = 40960, bVU2 = 57344, bO1 = 61440;

  hipMemsetAsync((void*)(w + oScal), 0, 64 * 4, stream);
  hipMemsetAsync((void*)cntID, 0, (size_t)CON_N * 4, stream);
  hipMemsetAsync((void*)cntIS, 0, (size_t)VAR_N * 4, stream);
  hipMemsetAsync((void*)cntED, 0, (size_t)EQ_N  * 4, stream);
  hipMemsetAsync((void*)cntES, 0, (size_t)VAR_N * 4, stream);

  {
    PrepArgs pa;
    const float* srcs[9] = { q_w1, q_w2, cu_w1, cu_w2, ec_w1, ec_w2, vu_w1, vu_w2, o_w1 };
    int Ks[9]   = { 64, 64, 128, 64, 128, 64, 256, 64, 64 };
    int Cs[9]   = { 64, 64, 64, 128, 64, 128, 64, 64, 64 };
    int bases[9]= { bQ1, bQ2, bCU1, bCU2, bEC1, bEC2, bVU1, bVU2, bO1 };
    for (int i = 0; i < 9; ++i) {
      pa.src[i] = srcs[i]; pa.K[i] = Ks[i]; pa.C[i] = Cs[i];
      pa.base[i] = bases[i]; pa.end[i] = bases[i] + Ks[i] * Cs[i];
    }
    prep_wt_k<<<(65536 + 255) / 256, 256, 0, stream>>>(pa, wtBase);
  }

  build_all_k<<<(NNZ_I + NNZ_E + 255) / 256, 256, 0, stream>>>(
      isrc, idst, ival, esrc, edst, evalv,
      cntID, listID, cntIS, listIS, cntED, listED, cntES, listES);
  sumsq_k<<<64, 256, 0, stream>>>(obj, VAR_N, scal);
  init_rows_k<<<(VAR_N + CON_N + EQ_N + 3) / 4, 256, 0, stream>>>(
      relaxed, cntID, listID, cntED, listED, w + oVarA, w + oCons, w + oEqc);

  float* varCur = w + oVarA;
  float* varNxt = w + oVarB;

  GemmSide Z = {};

  const int nbV = (VAR_N + 63) / 64;   // 782
  const int nbC = (CON_N + 63) / 64;   // 782
  const int nbE = (EQ_N + 63) / 64;    // 157

  for (int p = 0; p < NPASS; ++p) {
    float* ssq = scal + 1 + p * 5;   // [q, cu, ec, vu, o]

    // q-MLP layer 1: H = [varCur|noise] @ q_w1 + b1, ss -> ssq0
    {
      GemmSide S = { varCur, nullptr, wtBase + bQ1, q_w1, q_b1, w + oH, nullptr,
                     nullptr, ssq + 0, 1.0f,
                     noise + (size_t)p * VAR_N * 4, nullptr, nullptr, VAR_N, nbV };
      mlp_gemm<64, 64, 0, 1, false, true, 0><<<nbV, 256, 0, stream>>>(S, Z);
    }
    // q-MLP layer 2: qry = relu-norm(H) @ q_w2 + b2 + 0.5*mask
    {
      GemmSide S = { w + oH, nullptr, wtBase + bQ2, q_w2, q_b2, w + oQry, (float*)mask,
                     ssq + 0, nullptr, (float)VAR_N,
                     nullptr, nullptr, nullptr, VAR_N, nbV };
      mlp_gemm<64, 64, 0, 0, true, false, 1><<<nbV, 256, 0, stream>>>(S, Z);
    }
    // fused loss gathers
    gather_loss_k<<<(CON_N + 3) / 4 + (EQ_N + 3) / 4, 256, 0, stream>>>(
        cntID, listID, cntED, listED, w + oQry, cv, ecv, w + oCloss, w + oEloss);
    // cu/ec MLP layer 1 (batched)
    {
      GemmSide Sa = { w + oCons, w + oCloss, wtBase + bCU1, cu_w1, cu_b1, w + oH, nullptr,
                      nullptr, ssq + 1, 1.0f, nullptr, nullptr, nullptr, CON_N, nbC };
      GemmSide Sb = { w + oEqc, w + oEloss, wtBase + bEC1, ec_w1, ec_b1, w + oHE, nullptr,
                      nullptr, ssq + 2, 1.0f, nullptr, nullptr, nullptr, EQ_N, nbE };
      mlp_gemm<128, 64, 1, 0, false, true, 0><<<nbC + nbE, 256, 0, stream>>>(Sa, Sb);
    }
    // cu/ec MLP layer 2 (batched, fused state update)
    {
      GemmSide Sa = { w + oH, nullptr, wtBase + bCU2, cu_w2, cu_b2, w + oCtmp, w + oCons,
                      ssq + 1, nullptr, (float)CON_N, nullptr, nullptr, nullptr, CON_N, nbC };
      GemmSide Sb = { w + oHE, nullptr, wtBase + bEC2, ec_w2, ec_b2, w + oEtmp, w + oEqc,
                      ssq + 2, nullptr, (float)EQ_N, nullptr, nullptr, nullptr, EQ_N, nbE };
      mlp_gemm<64, 128, 0, 0, true, false, 3><<<nbC + nbE, 256, 0, stream>>>(Sa, Sb);
    }
    // var message gather
    gather_vmsg_k<<<(VAR_N + 3) / 4, 256, 0, stream>>>(
        cntIS, listIS, cntES, listES, w + oCtmp, w + oEtmp, w + oMsgs);
    // vu layer 1: H = [varCur|msgs|objn|mask] @ vu_w1, ss -> ssq3
    {
      GemmSide S = { varCur, w + oMsgs, wtBase + bVU1, vu_w1, vu_b1, w + oH, nullptr,
                     nullptr, ssq + 3, 1.0f, obj, mask, scal, VAR_N, nbV };
      mlp_gemm<256, 64, 1, 2, false, true, 0><<<nbV, 256, 0, stream>>>(S, Z);
    }
    // vu layer 2: varNxt = relu-norm(H)@vu_w2 + b2 + 0.5*varCur
    {
      GemmSide S = { w + oH, nullptr, wtBase + bVU2, vu_w2, vu_b2, varNxt, varCur,
                     ssq + 3, nullptr, (float)VAR_N, nullptr, nullptr, nullptr, VAR_N, nbV };
      mlp_gemm<64, 64, 0, 0, true, false, 2><<<nbV, 256, 0, stream>>>(S, Z);
    }
    // o layer 1: H = varNxt @ o_w1 + b1, ss -> ssq4
    {
      GemmSide S = { varNxt, nullptr, wtBase + bO1, o_w1, o_b1, w + oH, nullptr,
                     nullptr, ssq + 4, 1.0f, nullptr, nullptr, nullptr, VAR_N, nbV };
      mlp_gemm<64, 64, 0, 0, false, true, 0><<<nbV, 256, 0, stream>>>(S, Z);
    }
    out_k<<<(VAR_N + 3) / 4, 256, 0, stream>>>(w + oH, ssq + 4, o_w2, o_b2, mask, dout, p);

    float* t = varCur; varCur = varNxt; varNxt = t;
  }
}

// Round 7
// 1194.259 us; speedup vs baseline: 1.4335x; 1.4335x over previous
//
#include <hip/hip_runtime.h>
#include <hip/hip_fp16.h>
#include <math.h>

// MIPNetwork: 3-pass GNN. F=64. Round 7: hybrid MFMA GEMM —
// full W staged to LDS once per block (padded, 16B-aligned), then
// barrier-free waves grid-stride over 16-row strips with A-frags
// loaded straight from global (all K-steps issued back-to-back).
// inv_s folded into epilogue; ss atomics spread over 8 cells.

constexpr int VAR_N = 50000;
constexpr int CON_N = 50000;
constexpr int EQ_N  = 10000;
constexpr int NNZ_I = 800000;
constexpr int NNZ_E = 200000;
constexpr int NPASS = 3;

constexpr int CAP_ID = 48;
constexpr int CAP_IS = 48;
constexpr int CAP_ED = 64;
constexpr int CAP_ES = 24;

typedef _Float16 f16x8 __attribute__((ext_vector_type(8)));
typedef float    f32x4 __attribute__((ext_vector_type(4)));

__device__ __forceinline__ float wred(float v) {
#pragma unroll
  for (int o = 32; o > 0; o >>= 1) v += __shfl_down(v, o, 64);
  return v;
}

__device__ __forceinline__ float unpack_val(unsigned e) {
  return __half2float(__ushort_as_half((unsigned short)(e & 0xFFFFu)));
}

// 8-cell spread sum-of-squares (cells 64B apart to parallelize atomics)
__device__ __forceinline__ float cellsum(const float* p) {
  float s = 0.0f;
#pragma unroll
  for (int i = 0; i < 8; ++i) s += p[i * 16];
  return s;
}

// ---------------- weight prep: f32 [K][C] -> f16 transposed [C][K] ----------------
struct PrepArgs {
  const float* src[9];
  int K[9]; int C[9]; int base[9]; int end[9];
};

__global__ __launch_bounds__(256) void prep_wt_k(PrepArgs a, __half* __restrict__ wt)
{
  int idx = blockIdx.x * 256 + threadIdx.x;
  if (idx >= 65536) return;
#pragma unroll
  for (int i = 0; i < 9; ++i) {
    if (idx < a.end[i]) {
      int local = idx - a.base[i];
      int k = local % a.K[i];
      int c = local / a.K[i];
      wt[idx] = __float2half_rn(a.src[i][(size_t)k * a.C[i] + c]);
      return;
    }
  }
}

// ---------------- MFMA GEMM (W-in-LDS once, barrier-free strips) ----------------
// out[N x COLS] = X[N x K] @ W + bias
// MODE 0: X = X0[N x K]; MODE 1: X = concat(X0[N x 64], X1[N x (K-64)])
// EXTRA 0: none; 1: += noise4 @ Wf32[K..K+3]; 2: += (obj*oscale, mask) @ Wf32[K..K+1]
// RELUNORM: A = relu(X); epilogue scales acc by inv_s = rsqrt(1e-6 + ss/ssdiv)
// OUT_SS: block-reduced sum(out^2) -> ssout[8 spread cells]
// POSTOP 0: out=v; 1: out=v+0.5*aux[row]; 2: out=v+0.5*aux[row*64+col];
//        3: col<64: aux[row*64+col]=v+0.5*aux; col>=64: out[row*64+col-64]=v
struct GemmSide {
  const float* X0; const float* X1;
  const __half* WT;                     // f16 transposed [COLS][K]
  const float* W;  const float* bias;   // f32 originals (epilogue extras)
  float* out; float* aux;
  const float* ssin; float* ssout; float ssdiv;
  const float* exA; const float* exB; const float* exScale;
  int N; int nblk;
};

template<int K, int COLS, int MODE, int EXTRA, bool RELUNORM, bool OUT_SS, int POSTOP>
__global__ __launch_bounds__(256) void mlp_gemm(GemmSide A, GemmSide B)
{
  constexpr int NCB = COLS / 16;
  constexpr int NS  = K / 32;
  constexpr int KP  = K + 8;            // padded LDS stride in halves; (K+8)*2 % 16 == 0
  __shared__ __half Wl[COLS * KP];
  __shared__ float red[4];

  const bool inA = (blockIdx.x < (unsigned)A.nblk);
  const GemmSide& S = inA ? A : B;
  const int bid = blockIdx.x - (inA ? 0 : A.nblk);
  const int nblk = inA ? A.nblk : B.nblk;

  const int tid = threadIdx.x, lane = tid & 63, wid = tid >> 6;
  const int lr = lane & 15;             // fragment row/col index
  const int kgrp = (lane >> 4) * 8;     // k-offset within 32-step

  // stage full W to LDS, coalesced 16B copies
  for (int idx = tid; idx < COLS * (K / 8); idx += 256) {
    int c = idx / (K / 8), seg = idx % (K / 8);
    *(f16x8*)&Wl[c * KP + seg * 8] = *(const f16x8*)(S.WT + (size_t)c * K + seg * 8);
  }
  __syncthreads();

  float inv_s = 1.0f;
  if constexpr (RELUNORM) inv_s = rsqrtf(1e-6f + cellsum(S.ssin) / S.ssdiv);
  float oscale = 0.0f;
  if constexpr (EXTRA == 2) oscale = 1.0f / (sqrtf((*S.exScale) * (1.0f / VAR_N)) + 1e-6f);

  // column-constant epilogue data
  float bcol[NCB], ew0[NCB], ew1[NCB], ew2[NCB], ew3[NCB];
#pragma unroll
  for (int c = 0; c < NCB; ++c) {
    int col = c * 16 + lr;
    bcol[c] = S.bias[col];
    if constexpr (EXTRA == 1) {
      ew0[c] = S.W[(size_t)(K + 0) * COLS + col];
      ew1[c] = S.W[(size_t)(K + 1) * COLS + col];
      ew2[c] = S.W[(size_t)(K + 2) * COLS + col];
      ew3[c] = S.W[(size_t)(K + 3) * COLS + col];
    }
    if constexpr (EXTRA == 2) {
      ew0[c] = S.W[(size_t)(K + 0) * COLS + col];
      ew1[c] = S.W[(size_t)(K + 1) * COLS + col];
    }
  }

  const int nStrips = (S.N + 15) / 16;
  const int nw = nblk * 4;
  float ssloc = 0.0f;

  for (int strip = bid * 4 + wid; strip < nStrips; strip += nw) {
    const int row0 = strip * 16;
    const int arow = row0 + lr;
    const bool rok = arow < S.N;

    // issue all A loads back-to-back (2*NS outstanding 16B loads)
    float4 u[NS], v[NS];
#pragma unroll
    for (int s = 0; s < NS; ++s) {
      if (rok) {
        const int gk = s * 32 + kgrp;
        const float* p;
        if constexpr (MODE == 0) p = S.X0 + (size_t)arow * K + gk;
        else p = (gk < 64) ? (S.X0 + ((size_t)arow << 6) + gk)
                           : (S.X1 + (size_t)arow * (K - 64) + (gk - 64));
        u[s] = *(const float4*)p;
        v[s] = *(const float4*)(p + 4);
      } else {
        u[s] = make_float4(0.f, 0.f, 0.f, 0.f);
        v[s] = make_float4(0.f, 0.f, 0.f, 0.f);
      }
    }

    f32x4 acc[NCB] = {};
#pragma unroll
    for (int s = 0; s < NS; ++s) {
      float4 uu = u[s], vv = v[s];
      if constexpr (RELUNORM) {
        uu.x = fmaxf(uu.x, 0.f); uu.y = fmaxf(uu.y, 0.f);
        uu.z = fmaxf(uu.z, 0.f); uu.w = fmaxf(uu.w, 0.f);
        vv.x = fmaxf(vv.x, 0.f); vv.y = fmaxf(vv.y, 0.f);
        vv.z = fmaxf(vv.z, 0.f); vv.w = fmaxf(vv.w, 0.f);
      }
      f16x8 af;
      af[0] = (_Float16)uu.x; af[1] = (_Float16)uu.y;
      af[2] = (_Float16)uu.z; af[3] = (_Float16)uu.w;
      af[4] = (_Float16)vv.x; af[5] = (_Float16)vv.y;
      af[6] = (_Float16)vv.z; af[7] = (_Float16)vv.w;
#pragma unroll
      for (int c = 0; c < NCB; ++c) {
        const f16x8 bf = *(const f16x8*)&Wl[(c * 16 + lr) * KP + s * 32 + kgrp];
        acc[c] = __builtin_amdgcn_mfma_f32_16x16x32_f16(af, bf, acc[c], 0, 0, 0);
      }
    }

    // epilogue
#pragma unroll
    for (int j = 0; j < 4; ++j) {
      int grow = row0 + ((lane >> 4) << 2) + j;
      if (grow < S.N) {
        float nx = 0, ny = 0, nz = 0, nw4 = 0, ov = 0, mv = 0;
        if constexpr (EXTRA == 1) {
          float4 n4 = *reinterpret_cast<const float4*>(&S.exA[(size_t)grow * 4]);
          nx = n4.x; ny = n4.y; nz = n4.z; nw4 = n4.w;
        }
        if constexpr (EXTRA == 2) { ov = S.exA[grow] * oscale; mv = S.exB[grow]; }
#pragma unroll
        for (int c = 0; c < NCB; ++c) {
          int col = c * 16 + lr;
          float vv2 = acc[c][j];
          if constexpr (RELUNORM) vv2 *= inv_s;
          vv2 += bcol[c];
          if constexpr (EXTRA == 1)
            vv2 = fmaf(nx, ew0[c], fmaf(ny, ew1[c], fmaf(nz, ew2[c], fmaf(nw4, ew3[c], vv2))));
          if constexpr (EXTRA == 2)
            vv2 = fmaf(ov, ew0[c], fmaf(mv, ew1[c], vv2));
          if constexpr (POSTOP == 1) vv2 += 0.5f * S.aux[grow];
          if constexpr (POSTOP == 2) vv2 += 0.5f * S.aux[((size_t)grow << 6) + col];
          if constexpr (POSTOP == 3) {
            if (col < 64) {
              float nv = vv2 + 0.5f * S.aux[((size_t)grow << 6) + col];
              S.aux[((size_t)grow << 6) + col] = nv;
            } else {
              S.out[((size_t)grow << 6) + (col - 64)] = vv2;
            }
          } else {
            S.out[(size_t)grow * COLS + col] = vv2;
          }
          if constexpr (OUT_SS) ssloc = fmaf(vv2, vv2, ssloc);
        }
      }
    }
  }

  if constexpr (OUT_SS) {
    ssloc = wred(ssloc);
    if (lane == 0) red[wid] = ssloc;
    __syncthreads();
    if (tid == 0) {
      float s = red[0] + red[1] + red[2] + red[3];
      atomicAdd(&S.ssout[(blockIdx.x & 7) * 16], s);
    }
  }
}

// ---------------- adjacency build: packed-list append ----------------
__global__ __launch_bounds__(256) void build_all_k(
    const int* __restrict__ isrc, const int* __restrict__ idst, const float* __restrict__ ival,
    const int* __restrict__ esrc, const int* __restrict__ edst, const float* __restrict__ evalv,
    int* __restrict__ cntID, unsigned* __restrict__ listID,
    int* __restrict__ cntIS, unsigned* __restrict__ listIS,
    int* __restrict__ cntED, unsigned* __restrict__ listED,
    int* __restrict__ cntES, unsigned* __restrict__ listES)
{
  int gid = blockIdx.x * 256 + threadIdx.x;
  if (gid < NNZ_I) {
    int s = isrc[gid], d = idst[gid];
    unsigned hb = (unsigned)__half_as_ushort(__float2half_rn(ival[gid]));
    int pd = atomicAdd(&cntID[d], 1);
    if (pd < CAP_ID) listID[(size_t)d * CAP_ID + pd] = ((unsigned)s << 16) | hb;
    int ps = atomicAdd(&cntIS[s], 1);
    if (ps < CAP_IS) listIS[(size_t)s * CAP_IS + ps] = ((unsigned)d << 16) | hb;
  } else if (gid < NNZ_I + NNZ_E) {
    int e = gid - NNZ_I;
    int s = esrc[e], d = edst[e];
    unsigned hb = (unsigned)__half_as_ushort(__float2half_rn(evalv[e]));
    int pd = atomicAdd(&cntED[d], 1);
    if (pd < CAP_ED) listED[(size_t)d * CAP_ED + pd] = ((unsigned)s << 16) | hb;
    int ps = atomicAdd(&cntES[s], 1);
    if (ps < CAP_ES) listES[(size_t)s * CAP_ES + ps] = ((unsigned)d << 16) | hb;
  }
}

// ---------------- state init: one wave per row ----------------
__global__ __launch_bounds__(256) void init_rows_k(
    const float* __restrict__ relaxed,
    const int* __restrict__ cntID, const unsigned* __restrict__ listID,
    const int* __restrict__ cntED, const unsigned* __restrict__ listED,
    float* __restrict__ variables, float* __restrict__ constraints, float* __restrict__ eqcons)
{
  int widx = blockIdx.x * 4 + (threadIdx.x >> 6);
  int lane = threadIdx.x & 63;
  if (widx < VAR_N) {
    variables[((size_t)widx << 6) + lane] = relaxed[widx];
  } else if (widx < VAR_N + CON_N) {
    int i = widx - VAR_N;
    int n = min(cntID[i], CAP_ID);
    float t = 0.0f;
    if (lane < n) {
      unsigned e = listID[(size_t)i * CAP_ID + lane];
      t = unpack_val(e) * relaxed[e >> 16];
    }
    t = wred(t);
    t = __shfl(t, 0, 64);
    constraints[((size_t)i << 6) + lane] = t;
  } else if (widx < VAR_N + CON_N + EQ_N) {
    int i = widx - VAR_N - CON_N;
    int n = min(cntED[i], CAP_ED);
    float t = 0.0f;
    if (lane < n) {
      unsigned e = listED[(size_t)i * CAP_ED + lane];
      t = unpack_val(e) * relaxed[e >> 16];
    }
    t = wred(t);
    t = __shfl(t, 0, 64);
    eqcons[((size_t)i << 6) + lane] = t;
  }
}

// ---------------- fused loss gathers ----------------
__global__ __launch_bounds__(256) void gather_loss_k(
    const int* __restrict__ cntC, const unsigned* __restrict__ listC,
    const int* __restrict__ cntE, const unsigned* __restrict__ listE,
    const float* __restrict__ qry,
    const float* __restrict__ cv, const float* __restrict__ ecv,
    float* __restrict__ closs, float* __restrict__ eloss)
{
  constexpr int nbC = (CON_N + 3) / 4;
  int b = blockIdx.x;
  int lane = threadIdx.x & 63;
  if (b < nbC) {
    int i = b * 4 + (threadIdx.x >> 6);
    if (i >= CON_N) return;
    int n = min(cntC[i], CAP_ID);
    const unsigned* lst = listC + (size_t)i * CAP_ID;
    float acc = 0.0f, ss = 0.0f;
    for (int j = 0; j < n; ++j) {
      unsigned e = lst[j];
      float v = unpack_val(e);
      acc = fmaf(v, qry[((size_t)(e >> 16) << 6) + lane], acc);
      ss  = fmaf(v, v, ss);
    }
    closs[((size_t)i << 6) + lane] = (acc - cv[i]) * rsqrtf(ss + 1e-6f);
  } else {
    int i = (b - nbC) * 4 + (threadIdx.x >> 6);
    if (i >= EQ_N) return;
    int n = min(cntE[i], CAP_ED);
    const unsigned* lst = listE + (size_t)i * CAP_ED;
    float acc = 0.0f, ss = 0.0f;
    for (int j = 0; j < n; ++j) {
      unsigned e = lst[j];
      float v = unpack_val(e);
      acc = fmaf(v, qry[((size_t)(e >> 16) << 6) + lane], acc);
      ss  = fmaf(v, v, ss);
    }
    float t = (ecv[i] - acc) * rsqrtf(ss + 1e-6f);
    eloss[((size_t)i << 6) + lane] = t * t;
  }
}

// ---------------- var-message gather ----------------
__global__ __launch_bounds__(256) void gather_vmsg_k(
    const int* __restrict__ cntS, const unsigned* __restrict__ listS,
    const int* __restrict__ cntES, const unsigned* __restrict__ listES,
    const float* __restrict__ ctmpHi, const float* __restrict__ etmpHi,
    float* __restrict__ msgs)
{
  int i = blockIdx.x * 4 + (threadIdx.x >> 6);
  if (i >= VAR_N) return;
  int lane = threadIdx.x & 63;

  float pos = 0.0f, neg = 0.0f, vss = 0.0f;
  {
    int n = min(cntS[i], CAP_IS);
    const unsigned* lst = listS + (size_t)i * CAP_IS;
    for (int j = 0; j < n; ++j) {
      unsigned e = lst[j];
      float v = unpack_val(e);
      float c = ctmpHi[((size_t)(e >> 16) << 6) + lane];
      vss = fmaf(v, v, vss);
      if (v > 0.0f) pos = fmaf(v, c, pos);
      else          neg = fmaf(-v, c, neg);
    }
  }
  float e2v = 0.0f;
  {
    int n = min(cntES[i], CAP_ES);
    const unsigned* lst = listES + (size_t)i * CAP_ES;
    for (int j = 0; j < n; ++j) {
      unsigned e = lst[j];
      e2v = fmaf(unpack_val(e), etmpHi[((size_t)(e >> 16) << 6) + lane], e2v);
    }
  }
  float ivs = rsqrtf(vss + 1e-6f);
  float* row = msgs + (size_t)i * 192;
  row[lane]       = pos * ivs;
  row[64 + lane]  = neg * ivs;
  row[128 + lane] = e2v;
}

// ---------------- small kernels ----------------
__global__ __launch_bounds__(256) void sumsq_k(const float* __restrict__ x, int n, float* out)
{
  float s = 0.0f;
  for (int i = blockIdx.x * 256 + threadIdx.x; i < n; i += gridDim.x * 256) {
    float v = x[i]; s = fmaf(v, v, s);
  }
  s = wred(s);
  __shared__ float red[4];
  int lane = threadIdx.x & 63, wid = threadIdx.x >> 6;
  if (lane == 0) red[wid] = s;
  __syncthreads();
  if (threadIdx.x == 0) atomicAdd(out, red[0] + red[1] + red[2] + red[3]);
}

__global__ __launch_bounds__(256) void out_k(
    const float* __restrict__ H, const float* __restrict__ ssin,
    const float* __restrict__ ow2, const float* __restrict__ ob2,
    const float* __restrict__ mask, float* __restrict__ dout, int pass)
{
  int row = blockIdx.x * 4 + (threadIdx.x >> 6);
  if (row >= VAR_N) return;
  int lane = threadIdx.x & 63;
  float inv_s = rsqrtf(1e-6f + cellsum(ssin) / (float)VAR_N);
  float t = fmaxf(H[(size_t)row * 64 + lane] * inv_s, 0.0f) * ow2[lane];
  t = wred(t);
  if (lane == 0) {
    float ov = t + ob2[0];
    float m = mask[row];
    float sig = 1.0f / (1.0f + expf(-ov));
    dout[pass * VAR_N + row] = sig * m + ov * (1.0f - m) * 0.1f;
    if (pass == NPASS - 1) dout[3 * VAR_N + row] = ov;
  }
}

// ---------------- launch ----------------
extern "C" void kernel_launch(void* const* d_in, const int* in_sizes, int n_in,
                              void* d_out, int out_size, void* d_ws, size_t ws_size,
                              hipStream_t stream)
{
  const int*   isrc = (const int*)  d_in[0];
  const int*   idst = (const int*)  d_in[1];
  const float* ival = (const float*)d_in[2];
  const int*   esrc = (const int*)  d_in[3];
  const int*   edst = (const int*)  d_in[4];
  const float* evalv= (const float*)d_in[5];
  const float* cv   = (const float*)d_in[6];
  const float* ecv  = (const float*)d_in[7];
  const float* relaxed = (const float*)d_in[8];
  const float* obj  = (const float*)d_in[9];
  const float* mask = (const float*)d_in[10];
  const float* noise= (const float*)d_in[11];
  const float* q_w1 = (const float*)d_in[12];
  const float* q_b1 = (const float*)d_in[13];
  const float* q_w2 = (const float*)d_in[14];
  const float* q_b2 = (const float*)d_in[15];
  const float* cu_w1= (const float*)d_in[16];
  const float* cu_b1= (const float*)d_in[17];
  const float* cu_w2= (const float*)d_in[18];
  const float* cu_b2= (const float*)d_in[19];
  const float* ec_w1= (const float*)d_in[20];
  const float* ec_b1= (const float*)d_in[21];
  const float* ec_w2= (const float*)d_in[22];
  const float* ec_b2= (const float*)d_in[23];
  const float* vu_w1= (const float*)d_in[24];
  const float* vu_b1= (const float*)d_in[25];
  const float* vu_w2= (const float*)d_in[26];
  const float* vu_b2= (const float*)d_in[27];
  const float* o_w1 = (const float*)d_in[28];
  const float* o_b1 = (const float*)d_in[29];
  const float* o_w2 = (const float*)d_in[30];
  const float* o_b2 = (const float*)d_in[31];
  float* dout = (float*)d_out;
  float* w = (float*)d_ws;

  size_t off = 0;
  auto A = [&](size_t n){ size_t o = off; off += (n + 63) & ~(size_t)63; return o; };
  const size_t oVarA  = A((size_t)VAR_N * 64);
  const size_t oVarB  = A((size_t)VAR_N * 64);
  const size_t oCons  = A((size_t)CON_N * 64);
  const size_t oEqc   = A((size_t)EQ_N  * 64);
  const size_t oQry   = A((size_t)VAR_N * 64);
  const size_t oH     = A((size_t)VAR_N * 64);
  const size_t oHE    = A((size_t)EQ_N  * 64);
  const size_t oCtmp  = A((size_t)CON_N * 64);
  const size_t oEtmp  = A((size_t)EQ_N  * 64);
  const size_t oCloss = A((size_t)CON_N * 64);
  const size_t oEloss = A((size_t)EQ_N  * 64);
  const size_t oMsgs  = A((size_t)VAR_N * 192);
  const size_t oScal  = A(2048);    // [objss | 15 ss-slots x 128]
  const size_t oWT    = A(32768);   // 65536 halves
  const size_t oCntID = A(CON_N);
  const size_t oCntIS = A(VAR_N);
  const size_t oCntED = A(EQ_N);
  const size_t oCntES = A(VAR_N);
  const size_t oListID = A((size_t)CON_N * CAP_ID);
  const size_t oListIS = A((size_t)VAR_N * CAP_IS);
  const size_t oListED = A((size_t)EQ_N  * CAP_ED);
  const size_t oListES = A((size_t)VAR_N * CAP_ES);

  float* scal = w + oScal;
  __half* wtBase = (__half*)(w + oWT);
  int*  cntID = (int*)(w + oCntID);
  int*  cntIS = (int*)(w + oCntIS);
  int*  cntED = (int*)(w + oCntED);
  int*  cntES = (int*)(w + oCntES);
  unsigned* listID = (unsigned*)(w + oListID);
  unsigned* listIS = (unsigned*)(w + oListIS);
  unsigned* listED = (unsigned*)(w + oListED);
  unsigned* listES = (unsigned*)(w + oListES);

  // WT offsets (halves), layout [C][K] per matrix
  const int bQ1 = 0,      bQ2 = 4096,  bCU1 = 8192,  bCU2 = 16384, bEC1 = 24576;
  const int bEC2 = 32768, bVU1 = 40960, bVU2 = 57344, bO1 = 61440;

  hipMemsetAsync((void*)(w + oScal), 0, 2048 * 4, stream);
  hipMemsetAsync((void*)cntID, 0, (size_t)CON_N * 4, stream);
  hipMemsetAsync((void*)cntIS, 0, (size_t)VAR_N * 4, stream);
  hipMemsetAsync((void*)cntED, 0, (size_t)EQ_N  * 4, stream);
  hipMemsetAsync((void*)cntES, 0, (size_t)VAR_N * 4, stream);

  {
    PrepArgs pa;
    const float* srcs[9] = { q_w1, q_w2, cu_w1, cu_w2, ec_w1, ec_w2, vu_w1, vu_w2, o_w1 };
    int Ks[9]   = { 64, 64, 128, 64, 128, 64, 256, 64, 64 };
    int Cs[9]   = { 64, 64, 64, 128, 64, 128, 64, 64, 64 };
    int bases[9]= { bQ1, bQ2, bCU1, bCU2, bEC1, bEC2, bVU1, bVU2, bO1 };
    for (int i = 0; i < 9; ++i) {
      pa.src[i] = srcs[i]; pa.K[i] = Ks[i]; pa.C[i] = Cs[i];
      pa.base[i] = bases[i]; pa.end[i] = bases[i] + Ks[i] * Cs[i];
    }
    prep_wt_k<<<(65536 + 255) / 256, 256, 0, stream>>>(pa, wtBase);
  }

  build_all_k<<<(NNZ_I + NNZ_E + 255) / 256, 256, 0, stream>>>(
      isrc, idst, ival, esrc, edst, evalv,
      cntID, listID, cntIS, listIS, cntED, listED, cntES, listES);
  sumsq_k<<<64, 256, 0, stream>>>(obj, VAR_N, scal);
  init_rows_k<<<(VAR_N + CON_N + EQ_N + 3) / 4, 256, 0, stream>>>(
      relaxed, cntID, listID, cntED, listED, w + oVarA, w + oCons, w + oEqc);

  float* varCur = w + oVarA;
  float* varNxt = w + oVarB;

  GemmSide Z = {};
  const int NBV = 768;                 // single-side grid
  const int NBC = 640, NBE = 128;      // cu/ec batched split

  for (int p = 0; p < NPASS; ++p) {
    // per-pass ss slots (8 spread cells each): [q, cu, ec, vu, o]
    float* ssq0 = scal + 16 + (size_t)(p * 5 + 0) * 128;
    float* ssq1 = scal + 16 + (size_t)(p * 5 + 1) * 128;
    float* ssq2 = scal + 16 + (size_t)(p * 5 + 2) * 128;
    float* ssq3 = scal + 16 + (size_t)(p * 5 + 3) * 128;
    float* ssq4 = scal + 16 + (size_t)(p * 5 + 4) * 128;

    // q-MLP layer 1: H = [varCur|noise] @ q_w1 + b1, ss -> ssq0
    {
      GemmSide S = { varCur, nullptr, wtBase + bQ1, q_w1, q_b1, w + oH, nullptr,
                     nullptr, ssq0, 1.0f,
                     noise + (size_t)p * VAR_N * 4, nullptr, nullptr, VAR_N, NBV };
      mlp_gemm<64, 64, 0, 1, false, true, 0><<<NBV, 256, 0, stream>>>(S, Z);
    }
    // q-MLP layer 2: qry = relu-norm(H) @ q_w2 + b2 + 0.5*mask
    {
      GemmSide S = { w + oH, nullptr, wtBase + bQ2, q_w2, q_b2, w + oQry, (float*)mask,
                     ssq0, nullptr, (float)VAR_N,
                     nullptr, nullptr, nullptr, VAR_N, NBV };
      mlp_gemm<64, 64, 0, 0, true, false, 1><<<NBV, 256, 0, stream>>>(S, Z);
    }
    // fused loss gathers
    gather_loss_k<<<(CON_N + 3) / 4 + (EQ_N + 3) / 4, 256, 0, stream>>>(
        cntID, listID, cntED, listED, w + oQry, cv, ecv, w + oCloss, w + oEloss);
    // cu/ec MLP layer 1 (batched)
    {
      GemmSide Sa = { w + oCons, w + oCloss, wtBase + bCU1, cu_w1, cu_b1, w + oH, nullptr,
                      nullptr, ssq1, 1.0f, nullptr, nullptr, nullptr, CON_N, NBC };
      GemmSide Sb = { w + oEqc, w + oEloss, wtBase + bEC1, ec_w1, ec_b1, w + oHE, nullptr,
                      nullptr, ssq2, 1.0f, nullptr, nullptr, nullptr, EQ_N, NBE };
      mlp_gemm<128, 64, 1, 0, false, true, 0><<<NBC + NBE, 256, 0, stream>>>(Sa, Sb);
    }
    // cu/ec MLP layer 2 (batched, fused state update)
    {
      GemmSide Sa = { w + oH, nullptr, wtBase + bCU2, cu_w2, cu_b2, w + oCtmp, w + oCons,
                      ssq1, nullptr, (float)CON_N, nullptr, nullptr, nullptr, CON_N, NBC };
      GemmSide Sb = { w + oHE, nullptr, wtBase + bEC2, ec_w2, ec_b2, w + oEtmp, w + oEqc,
                      ssq2, nullptr, (float)EQ_N, nullptr, nullptr, nullptr, EQ_N, NBE };
      mlp_gemm<64, 128, 0, 0, true, false, 3><<<NBC + NBE, 256, 0, stream>>>(Sa, Sb);
    }
    // var message gather
    gather_vmsg_k<<<(VAR_N + 3) / 4, 256, 0, stream>>>(
        cntIS, listIS, cntES, listES, w + oCtmp, w + oEtmp, w + oMsgs);
    // vu layer 1: H = [varCur|msgs|objn|mask] @ vu_w1, ss -> ssq3
    {
      GemmSide S = { varCur, w + oMsgs, wtBase + bVU1, vu_w1, vu_b1, w + oH, nullptr,
                     nullptr, ssq3, 1.0f, obj, mask, scal, VAR_N, NBV };
      mlp_gemm<256, 64, 1, 2, false, true, 0><<<NBV, 256, 0, stream>>>(S, Z);
    }
    // vu layer 2: varNxt = relu-norm(H)@vu_w2 + b2 + 0.5*varCur
    {
      GemmSide S = { w + oH, nullptr, wtBase + bVU2, vu_w2, vu_b2, varNxt, varCur,
                     ssq3, nullptr, (float)VAR_N, nullptr, nullptr, nullptr, VAR_N, NBV };
      mlp_gemm<64, 64, 0, 0, true, false, 2><<<NBV, 256, 0, stream>>>(S, Z);
    }
    // o layer 1: H = varNxt @ o_w1 + b1, ss -> ssq4
    {
      GemmSide S = { varNxt, nullptr, wtBase + bO1, o_w1, o_b1, w + oH, nullptr,
                     nullptr, ssq4, 1.0f, nullptr, nullptr, nullptr, VAR_N, NBV };
      mlp_gemm<64, 64, 0, 0, false, true, 0><<<NBV, 256, 0, stream>>>(S, Z);
    }
    out_k<<<(VAR_N + 3) / 4, 256, 0, stream>>>(w + oH, ssq4, o_w2, o_b2, mask, dout, p);

    float* t = varCur; varCur = varNxt; varNxt = t;
  }
}

// Round 8
// 1039.541 us; speedup vs baseline: 1.6469x; 1.1488x over previous
//
#include <hip/hip_runtime.h>
#include <hip/hip_fp16.h>
#include <math.h>

// MIPNetwork: 3-pass GNN. F=64. Round 8: ILP-batched adjacency build
// (4 edges/thread: int4/float4 coalesced loads, 8 atomics in flight),
// uint4-batched list reads in gathers/init, merged cnt memsets.
// GEMM = round 7 hybrid MFMA (W-in-LDS once, barrier-free strips).

constexpr int VAR_N = 50000;
constexpr int CON_N = 50000;
constexpr int EQ_N  = 10000;
constexpr int NNZ_I = 800000;
constexpr int NNZ_E = 200000;
constexpr int NPASS = 3;

constexpr int CAP_ID = 48;
constexpr int CAP_IS = 48;
constexpr int CAP_ED = 64;
constexpr int CAP_ES = 24;

typedef _Float16 f16x8 __attribute__((ext_vector_type(8)));
typedef float    f32x4 __attribute__((ext_vector_type(4)));

__device__ __forceinline__ float wred(float v) {
#pragma unroll
  for (int o = 32; o > 0; o >>= 1) v += __shfl_down(v, o, 64);
  return v;
}

__device__ __forceinline__ float unpack_val(unsigned e) {
  return __half2float(__ushort_as_half((unsigned short)(e & 0xFFFFu)));
}

__device__ __forceinline__ unsigned u4get(const uint4& q, int k) {
  return k == 0 ? q.x : (k == 1 ? q.y : (k == 2 ? q.z : q.w));
}

// 8-cell spread sum-of-squares (cells 64B apart to parallelize atomics)
__device__ __forceinline__ float cellsum(const float* p) {
  float s = 0.0f;
#pragma unroll
  for (int i = 0; i < 8; ++i) s += p[i * 16];
  return s;
}

// ---------------- weight prep: f32 [K][C] -> f16 transposed [C][K] ----------------
struct PrepArgs {
  const float* src[9];
  int K[9]; int C[9]; int base[9]; int end[9];
};

__global__ __launch_bounds__(256) void prep_wt_k(PrepArgs a, __half* __restrict__ wt)
{
  int idx = blockIdx.x * 256 + threadIdx.x;
  if (idx >= 65536) return;
#pragma unroll
  for (int i = 0; i < 9; ++i) {
    if (idx < a.end[i]) {
      int local = idx - a.base[i];
      int k = local % a.K[i];
      int c = local / a.K[i];
      wt[idx] = __float2half_rn(a.src[i][(size_t)k * a.C[i] + c]);
      return;
    }
  }
}

// ---------------- MFMA GEMM (W-in-LDS once, barrier-free strips) ----------------
struct GemmSide {
  const float* X0; const float* X1;
  const __half* WT;                     // f16 transposed [COLS][K]
  const float* W;  const float* bias;   // f32 originals (epilogue extras)
  float* out; float* aux;
  const float* ssin; float* ssout; float ssdiv;
  const float* exA; const float* exB; const float* exScale;
  int N; int nblk;
};

template<int K, int COLS, int MODE, int EXTRA, bool RELUNORM, bool OUT_SS, int POSTOP>
__global__ __launch_bounds__(256) void mlp_gemm(GemmSide A, GemmSide B)
{
  constexpr int NCB = COLS / 16;
  constexpr int NS  = K / 32;
  constexpr int KP  = K + 8;            // padded LDS stride in halves
  __shared__ __half Wl[COLS * KP];
  __shared__ float red[4];

  const bool inA = (blockIdx.x < (unsigned)A.nblk);
  const GemmSide& S = inA ? A : B;
  const int bid = blockIdx.x - (inA ? 0 : A.nblk);
  const int nblk = inA ? A.nblk : B.nblk;

  const int tid = threadIdx.x, lane = tid & 63, wid = tid >> 6;
  const int lr = lane & 15;
  const int kgrp = (lane >> 4) * 8;

  for (int idx = tid; idx < COLS * (K / 8); idx += 256) {
    int c = idx / (K / 8), seg = idx % (K / 8);
    *(f16x8*)&Wl[c * KP + seg * 8] = *(const f16x8*)(S.WT + (size_t)c * K + seg * 8);
  }
  __syncthreads();

  float inv_s = 1.0f;
  if constexpr (RELUNORM) inv_s = rsqrtf(1e-6f + cellsum(S.ssin) / S.ssdiv);
  float oscale = 0.0f;
  if constexpr (EXTRA == 2) oscale = 1.0f / (sqrtf((*S.exScale) * (1.0f / VAR_N)) + 1e-6f);

  float bcol[NCB], ew0[NCB], ew1[NCB], ew2[NCB], ew3[NCB];
#pragma unroll
  for (int c = 0; c < NCB; ++c) {
    int col = c * 16 + lr;
    bcol[c] = S.bias[col];
    if constexpr (EXTRA == 1) {
      ew0[c] = S.W[(size_t)(K + 0) * COLS + col];
      ew1[c] = S.W[(size_t)(K + 1) * COLS + col];
      ew2[c] = S.W[(size_t)(K + 2) * COLS + col];
      ew3[c] = S.W[(size_t)(K + 3) * COLS + col];
    }
    if constexpr (EXTRA == 2) {
      ew0[c] = S.W[(size_t)(K + 0) * COLS + col];
      ew1[c] = S.W[(size_t)(K + 1) * COLS + col];
    }
  }

  const int nStrips = (S.N + 15) / 16;
  const int nw = nblk * 4;
  float ssloc = 0.0f;

  for (int strip = bid * 4 + wid; strip < nStrips; strip += nw) {
    const int row0 = strip * 16;
    const int arow = row0 + lr;
    const bool rok = arow < S.N;

    float4 u[NS], v[NS];
#pragma unroll
    for (int s = 0; s < NS; ++s) {
      if (rok) {
        const int gk = s * 32 + kgrp;
        const float* p;
        if constexpr (MODE == 0) p = S.X0 + (size_t)arow * K + gk;
        else p = (gk < 64) ? (S.X0 + ((size_t)arow << 6) + gk)
                           : (S.X1 + (size_t)arow * (K - 64) + (gk - 64));
        u[s] = *(const float4*)p;
        v[s] = *(const float4*)(p + 4);
      } else {
        u[s] = make_float4(0.f, 0.f, 0.f, 0.f);
        v[s] = make_float4(0.f, 0.f, 0.f, 0.f);
      }
    }

    f32x4 acc[NCB] = {};
#pragma unroll
    for (int s = 0; s < NS; ++s) {
      float4 uu = u[s], vv = v[s];
      if constexpr (RELUNORM) {
        uu.x = fmaxf(uu.x, 0.f); uu.y = fmaxf(uu.y, 0.f);
        uu.z = fmaxf(uu.z, 0.f); uu.w = fmaxf(uu.w, 0.f);
        vv.x = fmaxf(vv.x, 0.f); vv.y = fmaxf(vv.y, 0.f);
        vv.z = fmaxf(vv.z, 0.f); vv.w = fmaxf(vv.w, 0.f);
      }
      f16x8 af;
      af[0] = (_Float16)uu.x; af[1] = (_Float16)uu.y;
      af[2] = (_Float16)uu.z; af[3] = (_Float16)uu.w;
      af[4] = (_Float16)vv.x; af[5] = (_Float16)vv.y;
      af[6] = (_Float16)vv.z; af[7] = (_Float16)vv.w;
#pragma unroll
      for (int c = 0; c < NCB; ++c) {
        const f16x8 bf = *(const f16x8*)&Wl[(c * 16 + lr) * KP + s * 32 + kgrp];
        acc[c] = __builtin_amdgcn_mfma_f32_16x16x32_f16(af, bf, acc[c], 0, 0, 0);
      }
    }

#pragma unroll
    for (int j = 0; j < 4; ++j) {
      int grow = row0 + ((lane >> 4) << 2) + j;
      if (grow < S.N) {
        float nx = 0, ny = 0, nz = 0, nw4 = 0, ov = 0, mv = 0;
        if constexpr (EXTRA == 1) {
          float4 n4 = *reinterpret_cast<const float4*>(&S.exA[(size_t)grow * 4]);
          nx = n4.x; ny = n4.y; nz = n4.z; nw4 = n4.w;
        }
        if constexpr (EXTRA == 2) { ov = S.exA[grow] * oscale; mv = S.exB[grow]; }
#pragma unroll
        for (int c = 0; c < NCB; ++c) {
          int col = c * 16 + lr;
          float vv2 = acc[c][j];
          if constexpr (RELUNORM) vv2 *= inv_s;
          vv2 += bcol[c];
          if constexpr (EXTRA == 1)
            vv2 = fmaf(nx, ew0[c], fmaf(ny, ew1[c], fmaf(nz, ew2[c], fmaf(nw4, ew3[c], vv2))));
          if constexpr (EXTRA == 2)
            vv2 = fmaf(ov, ew0[c], fmaf(mv, ew1[c], vv2));
          if constexpr (POSTOP == 1) vv2 += 0.5f * S.aux[grow];
          if constexpr (POSTOP == 2) vv2 += 0.5f * S.aux[((size_t)grow << 6) + col];
          if constexpr (POSTOP == 3) {
            if (col < 64) {
              float nv = vv2 + 0.5f * S.aux[((size_t)grow << 6) + col];
              S.aux[((size_t)grow << 6) + col] = nv;
            } else {
              S.out[((size_t)grow << 6) + (col - 64)] = vv2;
            }
          } else {
            S.out[(size_t)grow * COLS + col] = vv2;
          }
          if constexpr (OUT_SS) ssloc = fmaf(vv2, vv2, ssloc);
        }
      }
    }
  }

  if constexpr (OUT_SS) {
    ssloc = wred(ssloc);
    if (lane == 0) red[wid] = ssloc;
    __syncthreads();
    if (tid == 0) {
      float s = red[0] + red[1] + red[2] + red[3];
      atomicAdd(&S.ssout[(blockIdx.x & 7) * 16], s);
    }
  }
}

// ---------------- adjacency build: 4 edges/thread, batched atomics ----------------
constexpr int QI = NNZ_I / 4;   // 200000
constexpr int QE = NNZ_E / 4;   // 50000

__global__ __launch_bounds__(256) void build_all_k(
    const int* __restrict__ isrc, const int* __restrict__ idst, const float* __restrict__ ival,
    const int* __restrict__ esrc, const int* __restrict__ edst, const float* __restrict__ evalv,
    int* __restrict__ cntID, unsigned* __restrict__ listID,
    int* __restrict__ cntIS, unsigned* __restrict__ listIS,
    int* __restrict__ cntED, unsigned* __restrict__ listED,
    int* __restrict__ cntES, unsigned* __restrict__ listES)
{
  int t = blockIdx.x * 256 + threadIdx.x;
  if (t < QI) {
    int4   s4 = *(const int4*)(isrc + 4 * t);
    int4   d4 = *(const int4*)(idst + 4 * t);
    float4 v4 = *(const float4*)(ival + 4 * t);
    int   ss[4] = { s4.x, s4.y, s4.z, s4.w };
    int   dd[4] = { d4.x, d4.y, d4.z, d4.w };
    float vv[4] = { v4.x, v4.y, v4.z, v4.w };
    unsigned hb[4]; int pd[4], ps[4];
#pragma unroll
    for (int k = 0; k < 4; ++k) hb[k] = (unsigned)__half_as_ushort(__float2half_rn(vv[k]));
#pragma unroll
    for (int k = 0; k < 4; ++k) pd[k] = atomicAdd(&cntID[dd[k]], 1);
#pragma unroll
    for (int k = 0; k < 4; ++k) ps[k] = atomicAdd(&cntIS[ss[k]], 1);
#pragma unroll
    for (int k = 0; k < 4; ++k)
      if (pd[k] < CAP_ID) listID[(size_t)dd[k] * CAP_ID + pd[k]] = ((unsigned)ss[k] << 16) | hb[k];
#pragma unroll
    for (int k = 0; k < 4; ++k)
      if (ps[k] < CAP_IS) listIS[(size_t)ss[k] * CAP_IS + ps[k]] = ((unsigned)dd[k] << 16) | hb[k];
  } else if (t < QI + QE) {
    int e = t - QI;
    int4   s4 = *(const int4*)(esrc + 4 * e);
    int4   d4 = *(const int4*)(edst + 4 * e);
    float4 v4 = *(const float4*)(evalv + 4 * e);
    int   ss[4] = { s4.x, s4.y, s4.z, s4.w };
    int   dd[4] = { d4.x, d4.y, d4.z, d4.w };
    float vv[4] = { v4.x, v4.y, v4.z, v4.w };
    unsigned hb[4]; int pd[4], ps[4];
#pragma unroll
    for (int k = 0; k < 4; ++k) hb[k] = (unsigned)__half_as_ushort(__float2half_rn(vv[k]));
#pragma unroll
    for (int k = 0; k < 4; ++k) pd[k] = atomicAdd(&cntED[dd[k]], 1);
#pragma unroll
    for (int k = 0; k < 4; ++k) ps[k] = atomicAdd(&cntES[ss[k]], 1);
#pragma unroll
    for (int k = 0; k < 4; ++k)
      if (pd[k] < CAP_ED) listED[(size_t)dd[k] * CAP_ED + pd[k]] = ((unsigned)ss[k] << 16) | hb[k];
#pragma unroll
    for (int k = 0; k < 4; ++k)
      if (ps[k] < CAP_ES) listES[(size_t)ss[k] * CAP_ES + ps[k]] = ((unsigned)dd[k] << 16) | hb[k];
  }
}

// ---------------- state init: one wave per row, uint4 entry loads ----------------
__global__ __launch_bounds__(256) void init_rows_k(
    const float* __restrict__ relaxed,
    const int* __restrict__ cntID, const unsigned* __restrict__ listID,
    const int* __restrict__ cntED, const unsigned* __restrict__ listED,
    float* __restrict__ variables, float* __restrict__ constraints, float* __restrict__ eqcons)
{
  int widx = blockIdx.x * 4 + (threadIdx.x >> 6);
  int lane = threadIdx.x & 63;
  if (widx < VAR_N) {
    variables[((size_t)widx << 6) + lane] = relaxed[widx];
  } else if (widx < VAR_N + CON_N) {
    int i = widx - VAR_N;
    int n = min(cntID[i], CAP_ID);
    float t = 0.0f;
    if (lane < n) {
      unsigned e = listID[(size_t)i * CAP_ID + lane];
      t = unpack_val(e) * relaxed[e >> 16];
    }
    t = wred(t);
    t = __shfl(t, 0, 64);
    constraints[((size_t)i << 6) + lane] = t;
  } else if (widx < VAR_N + CON_N + EQ_N) {
    int i = widx - VAR_N - CON_N;
    int n = min(cntED[i], CAP_ED);
    float t = 0.0f;
    if (lane < n) {
      unsigned e = listED[(size_t)i * CAP_ED + lane];
      t = unpack_val(e) * relaxed[e >> 16];
    }
    t = wred(t);
    t = __shfl(t, 0, 64);
    eqcons[((size_t)i << 6) + lane] = t;
  }
}

// ---------------- fused loss gathers (uint4 entry loads) ----------------
__global__ __launch_bounds__(256) void gather_loss_k(
    const int* __restrict__ cntC, const unsigned* __restrict__ listC,
    const int* __restrict__ cntE, const unsigned* __restrict__ listE,
    const float* __restrict__ qry,
    const float* __restrict__ cv, const float* __restrict__ ecv,
    float* __restrict__ closs, float* __restrict__ eloss)
{
  constexpr int nbC = (CON_N + 3) / 4;
  int b = blockIdx.x;
  int lane = threadIdx.x & 63;
  if (b < nbC) {
    int i = b * 4 + (threadIdx.x >> 6);
    if (i >= CON_N) return;
    int n = min(cntC[i], CAP_ID);
    const uint4* lst = (const uint4*)(listC + (size_t)i * CAP_ID);
    float acc = 0.0f, ss = 0.0f;
    for (int j4 = 0; j4 * 4 < n; ++j4) {
      uint4 q = lst[j4];
#pragma unroll
      for (int k = 0; k < 4; ++k) {
        int j = j4 * 4 + k;
        if (j < n) {
          unsigned e = u4get(q, k);
          float v = unpack_val(e);
          acc = fmaf(v, qry[((size_t)(e >> 16) << 6) + lane], acc);
          ss  = fmaf(v, v, ss);
        }
      }
    }
    closs[((size_t)i << 6) + lane] = (acc - cv[i]) * rsqrtf(ss + 1e-6f);
  } else {
    int i = (b - nbC) * 4 + (threadIdx.x >> 6);
    if (i >= EQ_N) return;
    int n = min(cntE[i], CAP_ED);
    const uint4* lst = (const uint4*)(listE + (size_t)i * CAP_ED);
    float acc = 0.0f, ss = 0.0f;
    for (int j4 = 0; j4 * 4 < n; ++j4) {
      uint4 q = lst[j4];
#pragma unroll
      for (int k = 0; k < 4; ++k) {
        int j = j4 * 4 + k;
        if (j < n) {
          unsigned e = u4get(q, k);
          float v = unpack_val(e);
          acc = fmaf(v, qry[((size_t)(e >> 16) << 6) + lane], acc);
          ss  = fmaf(v, v, ss);
        }
      }
    }
    float t = (ecv[i] - acc) * rsqrtf(ss + 1e-6f);
    eloss[((size_t)i << 6) + lane] = t * t;
  }
}

// ---------------- var-message gather (uint4 entry loads) ----------------
__global__ __launch_bounds__(256) void gather_vmsg_k(
    const int* __restrict__ cntS, const unsigned* __restrict__ listS,
    const int* __restrict__ cntES, const unsigned* __restrict__ listES,
    const float* __restrict__ ctmpHi, const float* __restrict__ etmpHi,
    float* __restrict__ msgs)
{
  int i = blockIdx.x * 4 + (threadIdx.x >> 6);
  if (i >= VAR_N) return;
  int lane = threadIdx.x & 63;

  float pos = 0.0f, neg = 0.0f, vss = 0.0f;
  {
    int n = min(cntS[i], CAP_IS);
    const uint4* lst = (const uint4*)(listS + (size_t)i * CAP_IS);
    for (int j4 = 0; j4 * 4 < n; ++j4) {
      uint4 q = lst[j4];
#pragma unroll
      for (int k = 0; k < 4; ++k) {
        int j = j4 * 4 + k;
        if (j < n) {
          unsigned e = u4get(q, k);
          float v = unpack_val(e);
          float c = ctmpHi[((size_t)(e >> 16) << 6) + lane];
          vss = fmaf(v, v, vss);
          if (v > 0.0f) pos = fmaf(v, c, pos);
          else          neg = fmaf(-v, c, neg);
        }
      }
    }
  }
  float e2v = 0.0f;
  {
    int n = min(cntES[i], CAP_ES);
    const uint4* lst = (const uint4*)(listES + (size_t)i * CAP_ES);
    for (int j4 = 0; j4 * 4 < n; ++j4) {
      uint4 q = lst[j4];
#pragma unroll
      for (int k = 0; k < 4; ++k) {
        int j = j4 * 4 + k;
        if (j < n) {
          unsigned e = u4get(q, k);
          e2v = fmaf(unpack_val(e), etmpHi[((size_t)(e >> 16) << 6) + lane], e2v);
        }
      }
    }
  }
  float ivs = rsqrtf(vss + 1e-6f);
  float* row = msgs + (size_t)i * 192;
  row[lane]       = pos * ivs;
  row[64 + lane]  = neg * ivs;
  row[128 + lane] = e2v;
}

// ---------------- small kernels ----------------
__global__ __launch_bounds__(256) void sumsq_k(const float* __restrict__ x, int n, float* out)
{
  float s = 0.0f;
  for (int i = blockIdx.x * 256 + threadIdx.x; i < n; i += gridDim.x * 256) {
    float v = x[i]; s = fmaf(v, v, s);
  }
  s = wred(s);
  __shared__ float red[4];
  int lane = threadIdx.x & 63, wid = threadIdx.x >> 6;
  if (lane == 0) red[wid] = s;
  __syncthreads();
  if (threadIdx.x == 0) atomicAdd(out, red[0] + red[1] + red[2] + red[3]);
}

__global__ __launch_bounds__(256) void out_k(
    const float* __restrict__ H, const float* __restrict__ ssin,
    const float* __restrict__ ow2, const float* __restrict__ ob2,
    const float* __restrict__ mask, float* __restrict__ dout, int pass)
{
  int row = blockIdx.x * 4 + (threadIdx.x >> 6);
  if (row >= VAR_N) return;
  int lane = threadIdx.x & 63;
  float inv_s = rsqrtf(1e-6f + cellsum(ssin) / (float)VAR_N);
  float t = fmaxf(H[(size_t)row * 64 + lane] * inv_s, 0.0f) * ow2[lane];
  t = wred(t);
  if (lane == 0) {
    float ov = t + ob2[0];
    float m = mask[row];
    float sig = 1.0f / (1.0f + expf(-ov));
    dout[pass * VAR_N + row] = sig * m + ov * (1.0f - m) * 0.1f;
    if (pass == NPASS - 1) dout[3 * VAR_N + row] = ov;
  }
}

// ---------------- launch ----------------
extern "C" void kernel_launch(void* const* d_in, const int* in_sizes, int n_in,
                              void* d_out, int out_size, void* d_ws, size_t ws_size,
                              hipStream_t stream)
{
  const int*   isrc = (const int*)  d_in[0];
  const int*   idst = (const int*)  d_in[1];
  const float* ival = (const float*)d_in[2];
  const int*   esrc = (const int*)  d_in[3];
  const int*   edst = (const int*)  d_in[4];
  const float* evalv= (const float*)d_in[5];
  const float* cv   = (const float*)d_in[6];
  const float* ecv  = (const float*)d_in[7];
  const float* relaxed = (const float*)d_in[8];
  const float* obj  = (const float*)d_in[9];
  const float* mask = (const float*)d_in[10];
  const float* noise= (const float*)d_in[11];
  const float* q_w1 = (const float*)d_in[12];
  const float* q_b1 = (const float*)d_in[13];
  const float* q_w2 = (const float*)d_in[14];
  const float* q_b2 = (const float*)d_in[15];
  const float* cu_w1= (const float*)d_in[16];
  const float* cu_b1= (const float*)d_in[17];
  const float* cu_w2= (const float*)d_in[18];
  const float* cu_b2= (const float*)d_in[19];
  const float* ec_w1= (const float*)d_in[20];
  const float* ec_b1= (const float*)d_in[21];
  const float* ec_w2= (const float*)d_in[22];
  const float* ec_b2= (const float*)d_in[23];
  const float* vu_w1= (const float*)d_in[24];
  const float* vu_b1= (const float*)d_in[25];
  const float* vu_w2= (const float*)d_in[26];
  const float* vu_b2= (const float*)d_in[27];
  const float* o_w1 = (const float*)d_in[28];
  const float* o_b1 = (const float*)d_in[29];
  const float* o_w2 = (const float*)d_in[30];
  const float* o_b2 = (const float*)d_in[31];
  float* dout = (float*)d_out;
  float* w = (float*)d_ws;

  size_t off = 0;
  auto A = [&](size_t n){ size_t o = off; off += (n + 63) & ~(size_t)63; return o; };
  const size_t oVarA  = A((size_t)VAR_N * 64);
  const size_t oVarB  = A((size_t)VAR_N * 64);
  const size_t oCons  = A((size_t)CON_N * 64);
  const size_t oEqc   = A((size_t)EQ_N  * 64);
  const size_t oQry   = A((size_t)VAR_N * 64);
  const size_t oH     = A((size_t)VAR_N * 64);
  const size_t oHE    = A((size_t)EQ_N  * 64);
  const size_t oCtmp  = A((size_t)CON_N * 64);
  const size_t oEtmp  = A((size_t)EQ_N  * 64);
  const size_t oCloss = A((size_t)CON_N * 64);
  const size_t oEloss = A((size_t)EQ_N  * 64);
  const size_t oMsgs  = A((size_t)VAR_N * 192);
  const size_t oScal  = A(2048);    // [objss | 15 ss-slots x 128]
  const size_t oWT    = A(32768);   // 65536 halves
  const size_t oCntID = A(CON_N);
  const size_t oCntIS = A(VAR_N);
  const size_t oCntED = A(EQ_N);
  const size_t oCntES = A(VAR_N);
  const size_t oListID = A((size_t)CON_N * CAP_ID);
  const size_t oListIS = A((size_t)VAR_N * CAP_IS);
  const size_t oListED = A((size_t)EQ_N  * CAP_ED);
  const size_t oListES = A((size_t)VAR_N * CAP_ES);

  float* scal = w + oScal;
  __half* wtBase = (__half*)(w + oWT);
  int*  cntID = (int*)(w + oCntID);
  int*  cntIS = (int*)(w + oCntIS);
  int*  cntED = (int*)(w + oCntED);
  int*  cntES = (int*)(w + oCntES);
  unsigned* listID = (unsigned*)(w + oListID);
  unsigned* listIS = (unsigned*)(w + oListIS);
  unsigned* listED = (unsigned*)(w + oListED);
  unsigned* listES = (unsigned*)(w + oListES);

  // WT offsets (halves), layout [C][K] per matrix
  const int bQ1 = 0,      bQ2 = 4096,  bCU1 = 8192,  bCU2 = 16384, bEC1 = 24576;
  const int bEC2 = 32768, bVU1 = 40960, bVU2 = 57344, bO1 = 61440;

  hipMemsetAsync((void*)(w + oScal), 0, 2048 * 4, stream);
  hipMemsetAsync((void*)(w + oCntID), 0, (oListID - oCntID) * 4, stream);  // all 4 cnt arrays

  {
    PrepArgs pa;
    const float* srcs[9] = { q_w1, q_w2, cu_w1, cu_w2, ec_w1, ec_w2, vu_w1, vu_w2, o_w1 };
    int Ks[9]   = { 64, 64, 128, 64, 128, 64, 256, 64, 64 };
    int Cs[9]   = { 64, 64, 64, 128, 64, 128, 64, 64, 64 };
    int bases[9]= { bQ1, bQ2, bCU1, bCU2, bEC1, bEC2, bVU1, bVU2, bO1 };
    for (int i = 0; i < 9; ++i) {
      pa.src[i] = srcs[i]; pa.K[i] = Ks[i]; pa.C[i] = Cs[i];
      pa.base[i] = bases[i]; pa.end[i] = bases[i] + Ks[i] * Cs[i];
    }
    prep_wt_k<<<(65536 + 255) / 256, 256, 0, stream>>>(pa, wtBase);
  }

  build_all_k<<<(QI + QE + 255) / 256, 256, 0, stream>>>(
      isrc, idst, ival, esrc, edst, evalv,
      cntID, listID, cntIS, listIS, cntED, listED, cntES, listES);
  sumsq_k<<<64, 256, 0, stream>>>(obj, VAR_N, scal);
  init_rows_k<<<(VAR_N + CON_N + EQ_N + 3) / 4, 256, 0, stream>>>(
      relaxed, cntID, listID, cntED, listED, w + oVarA, w + oCons, w + oEqc);

  float* varCur = w + oVarA;
  float* varNxt = w + oVarB;

  GemmSide Z = {};
  const int NBV = 768;                 // single-side grid
  const int NBC = 640, NBE = 128;      // cu/ec batched split

  for (int p = 0; p < NPASS; ++p) {
    float* ssq0 = scal + 16 + (size_t)(p * 5 + 0) * 128;
    float* ssq1 = scal + 16 + (size_t)(p * 5 + 1) * 128;
    float* ssq2 = scal + 16 + (size_t)(p * 5 + 2) * 128;
    float* ssq3 = scal + 16 + (size_t)(p * 5 + 3) * 128;
    float* ssq4 = scal + 16 + (size_t)(p * 5 + 4) * 128;

    // q-MLP layer 1: H = [varCur|noise] @ q_w1 + b1, ss -> ssq0
    {
      GemmSide S = { varCur, nullptr, wtBase + bQ1, q_w1, q_b1, w + oH, nullptr,
                     nullptr, ssq0, 1.0f,
                     noise + (size_t)p * VAR_N * 4, nullptr, nullptr, VAR_N, NBV };
      mlp_gemm<64, 64, 0, 1, false, true, 0><<<NBV, 256, 0, stream>>>(S, Z);
    }
    // q-MLP layer 2: qry = relu-norm(H) @ q_w2 + b2 + 0.5*mask
    {
      GemmSide S = { w + oH, nullptr, wtBase + bQ2, q_w2, q_b2, w + oQry, (float*)mask,
                     ssq0, nullptr, (float)VAR_N,
                     nullptr, nullptr, nullptr, VAR_N, NBV };
      mlp_gemm<64, 64, 0, 0, true, false, 1><<<NBV, 256, 0, stream>>>(S, Z);
    }
    // fused loss gathers
    gather_loss_k<<<(CON_N + 3) / 4 + (EQ_N + 3) / 4, 256, 0, stream>>>(
        cntID, listID, cntED, listED, w + oQry, cv, ecv, w + oCloss, w + oEloss);
    // cu/ec MLP layer 1 (batched)
    {
      GemmSide Sa = { w + oCons, w + oCloss, wtBase + bCU1, cu_w1, cu_b1, w + oH, nullptr,
                      nullptr, ssq1, 1.0f, nullptr, nullptr, nullptr, CON_N, NBC };
      GemmSide Sb = { w + oEqc, w + oEloss, wtBase + bEC1, ec_w1, ec_b1, w + oHE, nullptr,
                      nullptr, ssq2, 1.0f, nullptr, nullptr, nullptr, EQ_N, NBE };
      mlp_gemm<128, 64, 1, 0, false, true, 0><<<NBC + NBE, 256, 0, stream>>>(Sa, Sb);
    }
    // cu/ec MLP layer 2 (batched, fused state update)
    {
      GemmSide Sa = { w + oH, nullptr, wtBase + bCU2, cu_w2, cu_b2, w + oCtmp, w + oCons,
                      ssq1, nullptr, (float)CON_N, nullptr, nullptr, nullptr, CON_N, NBC };
      GemmSide Sb = { w + oHE, nullptr, wtBase + bEC2, ec_w2, ec_b2, w + oEtmp, w + oEqc,
                      ssq2, nullptr, (float)EQ_N, nullptr, nullptr, nullptr, EQ_N, NBE };
      mlp_gemm<64, 128, 0, 0, true, false, 3><<<NBC + NBE, 256, 0, stream>>>(Sa, Sb);
    }
    // var message gather
    gather_vmsg_k<<<(VAR_N + 3) / 4, 256, 0, stream>>>(
        cntIS, listIS, cntES, listES, w + oCtmp, w + oEtmp, w + oMsgs);
    // vu layer 1: H = [varCur|msgs|objn|mask] @ vu_w1, ss -> ssq3
    {
      GemmSide S = { varCur, w + oMsgs, wtBase + bVU1, vu_w1, vu_b1, w + oH, nullptr,
                     nullptr, ssq3, 1.0f, obj, mask, scal, VAR_N, NBV };
      mlp_gemm<256, 64, 1, 2, false, true, 0><<<NBV, 256, 0, stream>>>(S, Z);
    }
    // vu layer 2: varNxt = relu-norm(H)@vu_w2 + b2 + 0.5*varCur
    {
      GemmSide S = { w + oH, nullptr, wtBase + bVU2, vu_w2, vu_b2, varNxt, varCur,
                     ssq3, nullptr, (float)VAR_N, nullptr, nullptr, nullptr, VAR_N, NBV };
      mlp_gemm<64, 64, 0, 0, true, false, 2><<<NBV, 256, 0, stream>>>(S, Z);
    }
    // o layer 1: H = varNxt @ o_w1 + b1, ss -> ssq4
    {
      GemmSide S = { varNxt, nullptr, wtBase + bO1, o_w1, o_b1, w + oH, nullptr,
                     nullptr, ssq4, 1.0f, nullptr, nullptr, nullptr, VAR_N, NBV };
      mlp_gemm<64, 64, 0, 0, false, true, 0><<<NBV, 256, 0, stream>>>(S, Z);
    }
    out_k<<<(VAR_N + 3) / 4, 256, 0, stream>>>(w + oH, ssq4, o_w2, o_b2, mask, dout, p);

    float* t = varCur; varCur = varNxt; varNxt = t;
  }
}

// Round 9
// 947.099 us; speedup vs baseline: 1.8076x; 1.0976x over previous
//
#include <hip/hip_runtime.h>
#include <hip/hip_fp16.h>
#include <math.h>

// MIPNetwork: 3-pass GNN. F=64. Round 9: all intermediate feature buffers
// stored f16 (accumulation stays f32) — halves GEMM A/write traffic and
// gather traffic. Adjacency build at 2 edges/thread (ILP=4 atomics, ~95% occ).

constexpr int VAR_N = 50000;
constexpr int CON_N = 50000;
constexpr int EQ_N  = 10000;
constexpr int NNZ_I = 800000;
constexpr int NNZ_E = 200000;
constexpr int NPASS = 3;

constexpr int CAP_ID = 48;
constexpr int CAP_IS = 48;
constexpr int CAP_ED = 64;
constexpr int CAP_ES = 24;

typedef _Float16 f16x8 __attribute__((ext_vector_type(8)));
typedef float    f32x4 __attribute__((ext_vector_type(4)));
typedef _Float16 half_t;

__device__ __forceinline__ float wred(float v) {
#pragma unroll
  for (int o = 32; o > 0; o >>= 1) v += __shfl_down(v, o, 64);
  return v;
}

__device__ __forceinline__ float unpack_val(unsigned e) {
  return __half2float(__ushort_as_half((unsigned short)(e & 0xFFFFu)));
}

__device__ __forceinline__ unsigned u4get(const uint4& q, int k) {
  return k == 0 ? q.x : (k == 1 ? q.y : (k == 2 ? q.z : q.w));
}

// 8-cell spread sum-of-squares (cells 64B apart to parallelize atomics)
__device__ __forceinline__ float cellsum(const float* p) {
  float s = 0.0f;
#pragma unroll
  for (int i = 0; i < 8; ++i) s += p[i * 16];
  return s;
}

// ---------------- weight prep: f32 [K][C] -> f16 transposed [C][K] ----------------
struct PrepArgs {
  const float* src[9];
  int K[9]; int C[9]; int base[9]; int end[9];
};

__global__ __launch_bounds__(256) void prep_wt_k(PrepArgs a, half_t* __restrict__ wt)
{
  int idx = blockIdx.x * 256 + threadIdx.x;
  if (idx >= 65536) return;
#pragma unroll
  for (int i = 0; i < 9; ++i) {
    if (idx < a.end[i]) {
      int local = idx - a.base[i];
      int k = local % a.K[i];
      int c = local / a.K[i];
      wt[idx] = (half_t)a.src[i][(size_t)k * a.C[i] + c];
      return;
    }
  }
}

// ---------------- MFMA GEMM (W-in-LDS once, barrier-free strips, f16 I/O) ----------------
// out[N x COLS](f16) = X[N x K](f16) @ W + bias
// MODE 0: X = X0[N x K]; MODE 1: X = concat(X0[N x 64], X1[N x (K-64)])
// EXTRA 0: none; 1: += noise4 @ Wf32[K..K+3]; 2: += (obj*oscale, mask) @ Wf32[K..K+1]
// RELUNORM: A = relu(X); epilogue scales acc by inv_s = rsqrt(1e-6 + ss/ssdiv)
// OUT_SS: block-reduced sum(out^2) -> ssout[8 spread cells]
// POSTOP 0: out=v; 1: out=v+0.5*auxF[row]; 2: out=v+0.5*auxH[row*64+col];
//        3: col<64: auxH[row*64+col]=v+0.5*auxH; col>=64: out[row*64+col-64]=v
struct GemmSide {
  const half_t* X0; const half_t* X1;
  const half_t* WT;                     // f16 transposed [COLS][K]
  const float* W;  const float* bias;   // f32 originals (epilogue extras)
  half_t* out; half_t* auxH; const float* auxF;
  const float* ssin; float* ssout; float ssdiv;
  const float* exA; const float* exB; const float* exScale;
  int N; int nblk;
};

template<int K, int COLS, int MODE, int EXTRA, bool RELUNORM, bool OUT_SS, int POSTOP>
__global__ __launch_bounds__(256) void mlp_gemm(GemmSide A, GemmSide B)
{
  constexpr int NCB = COLS / 16;
  constexpr int NS  = K / 32;
  constexpr int KP  = K + 8;            // padded LDS stride in halves
  __shared__ half_t Wl[COLS * KP];
  __shared__ float red[4];

  const bool inA = (blockIdx.x < (unsigned)A.nblk);
  const GemmSide& S = inA ? A : B;
  const int bid = blockIdx.x - (inA ? 0 : A.nblk);
  const int nblk = inA ? A.nblk : B.nblk;

  const int tid = threadIdx.x, lane = tid & 63, wid = tid >> 6;
  const int lr = lane & 15;
  const int kgrp = (lane >> 4) * 8;

  for (int idx = tid; idx < COLS * (K / 8); idx += 256) {
    int c = idx / (K / 8), seg = idx % (K / 8);
    *(f16x8*)&Wl[c * KP + seg * 8] = *(const f16x8*)(S.WT + (size_t)c * K + seg * 8);
  }
  __syncthreads();

  float inv_s = 1.0f;
  if constexpr (RELUNORM) inv_s = rsqrtf(1e-6f + cellsum(S.ssin) / S.ssdiv);
  float oscale = 0.0f;
  if constexpr (EXTRA == 2) oscale = 1.0f / (sqrtf((*S.exScale) * (1.0f / VAR_N)) + 1e-6f);

  float bcol[NCB], ew0[NCB], ew1[NCB], ew2[NCB], ew3[NCB];
#pragma unroll
  for (int c = 0; c < NCB; ++c) {
    int col = c * 16 + lr;
    bcol[c] = S.bias[col];
    if constexpr (EXTRA == 1) {
      ew0[c] = S.W[(size_t)(K + 0) * COLS + col];
      ew1[c] = S.W[(size_t)(K + 1) * COLS + col];
      ew2[c] = S.W[(size_t)(K + 2) * COLS + col];
      ew3[c] = S.W[(size_t)(K + 3) * COLS + col];
    }
    if constexpr (EXTRA == 2) {
      ew0[c] = S.W[(size_t)(K + 0) * COLS + col];
      ew1[c] = S.W[(size_t)(K + 1) * COLS + col];
    }
  }

  const int nStrips = (S.N + 15) / 16;
  const int nw = nblk * 4;
  float ssloc = 0.0f;

  for (int strip = bid * 4 + wid; strip < nStrips; strip += nw) {
    const int row0 = strip * 16;
    const int arow = row0 + lr;
    const bool rok = arow < S.N;

    f16x8 af[NS];
#pragma unroll
    for (int s = 0; s < NS; ++s) {
      if (rok) {
        const int gk = s * 32 + kgrp;
        const half_t* p;
        if constexpr (MODE == 0) p = S.X0 + (size_t)arow * K + gk;
        else p = (gk < 64) ? (S.X0 + ((size_t)arow << 6) + gk)
                           : (S.X1 + (size_t)arow * (K - 64) + (gk - 64));
        af[s] = *(const f16x8*)p;
      } else {
        af[s] = f16x8{0, 0, 0, 0, 0, 0, 0, 0};
      }
    }

    f32x4 acc[NCB] = {};
#pragma unroll
    for (int s = 0; s < NS; ++s) {
      f16x8 a = af[s];
      if constexpr (RELUNORM) {
#pragma unroll
        for (int i = 0; i < 8; ++i) a[i] = a[i] > (half_t)0 ? a[i] : (half_t)0;
      }
#pragma unroll
      for (int c = 0; c < NCB; ++c) {
        const f16x8 bf = *(const f16x8*)&Wl[(c * 16 + lr) * KP + s * 32 + kgrp];
        acc[c] = __builtin_amdgcn_mfma_f32_16x16x32_f16(a, bf, acc[c], 0, 0, 0);
      }
    }

#pragma unroll
    for (int j = 0; j < 4; ++j) {
      int grow = row0 + ((lane >> 4) << 2) + j;
      if (grow < S.N) {
        float nx = 0, ny = 0, nz = 0, nw4 = 0, ov = 0, mv = 0;
        if constexpr (EXTRA == 1) {
          float4 n4 = *reinterpret_cast<const float4*>(&S.exA[(size_t)grow * 4]);
          nx = n4.x; ny = n4.y; nz = n4.z; nw4 = n4.w;
        }
        if constexpr (EXTRA == 2) { ov = S.exA[grow] * oscale; mv = S.exB[grow]; }
#pragma unroll
        for (int c = 0; c < NCB; ++c) {
          int col = c * 16 + lr;
          float vv2 = acc[c][j];
          if constexpr (RELUNORM) vv2 *= inv_s;
          vv2 += bcol[c];
          if constexpr (EXTRA == 1)
            vv2 = fmaf(nx, ew0[c], fmaf(ny, ew1[c], fmaf(nz, ew2[c], fmaf(nw4, ew3[c], vv2))));
          if constexpr (EXTRA == 2)
            vv2 = fmaf(ov, ew0[c], fmaf(mv, ew1[c], vv2));
          if constexpr (POSTOP == 1) vv2 += 0.5f * S.auxF[grow];
          if constexpr (POSTOP == 2) vv2 += 0.5f * (float)S.auxH[((size_t)grow << 6) + col];
          if constexpr (POSTOP == 3) {
            if (col < 64) {
              float nv = vv2 + 0.5f * (float)S.auxH[((size_t)grow << 6) + col];
              S.auxH[((size_t)grow << 6) + col] = (half_t)nv;
            } else {
              S.out[((size_t)grow << 6) + (col - 64)] = (half_t)vv2;
            }
          } else {
            S.out[(size_t)grow * COLS + col] = (half_t)vv2;
          }
          if constexpr (OUT_SS) ssloc = fmaf(vv2, vv2, ssloc);
        }
      }
    }
  }

  if constexpr (OUT_SS) {
    ssloc = wred(ssloc);
    if (lane == 0) red[wid] = ssloc;
    __syncthreads();
    if (tid == 0) {
      float s = red[0] + red[1] + red[2] + red[3];
      atomicAdd(&S.ssout[(blockIdx.x & 7) * 16], s);
    }
  }
}

// ---------------- adjacency build: 2 edges/thread, 4 atomics in flight ----------------
constexpr int QI2 = NNZ_I / 2;   // 400000
constexpr int QE2 = NNZ_E / 2;   // 100000

__global__ __launch_bounds__(256) void build_all_k(
    const int* __restrict__ isrc, const int* __restrict__ idst, const float* __restrict__ ival,
    const int* __restrict__ esrc, const int* __restrict__ edst, const float* __restrict__ evalv,
    int* __restrict__ cntID, unsigned* __restrict__ listID,
    int* __restrict__ cntIS, unsigned* __restrict__ listIS,
    int* __restrict__ cntED, unsigned* __restrict__ listED,
    int* __restrict__ cntES, unsigned* __restrict__ listES)
{
  int t = blockIdx.x * 256 + threadIdx.x;
  if (t < QI2) {
    int2   s2 = *(const int2*)(isrc + 2 * t);
    int2   d2 = *(const int2*)(idst + 2 * t);
    float2 v2 = *(const float2*)(ival + 2 * t);
    int   ss[2] = { s2.x, s2.y };
    int   dd[2] = { d2.x, d2.y };
    float vv[2] = { v2.x, v2.y };
    unsigned hb[2]; int pd[2], ps[2];
#pragma unroll
    for (int k = 0; k < 2; ++k) hb[k] = (unsigned)__half_as_ushort(__float2half_rn(vv[k]));
#pragma unroll
    for (int k = 0; k < 2; ++k) pd[k] = atomicAdd(&cntID[dd[k]], 1);
#pragma unroll
    for (int k = 0; k < 2; ++k) ps[k] = atomicAdd(&cntIS[ss[k]], 1);
#pragma unroll
    for (int k = 0; k < 2; ++k)
      if (pd[k] < CAP_ID) listID[(size_t)dd[k] * CAP_ID + pd[k]] = ((unsigned)ss[k] << 16) | hb[k];
#pragma unroll
    for (int k = 0; k < 2; ++k)
      if (ps[k] < CAP_IS) listIS[(size_t)ss[k] * CAP_IS + ps[k]] = ((unsigned)dd[k] << 16) | hb[k];
  } else if (t < QI2 + QE2) {
    int e = t - QI2;
    int2   s2 = *(const int2*)(esrc + 2 * e);
    int2   d2 = *(const int2*)(edst + 2 * e);
    float2 v2 = *(const float2*)(evalv + 2 * e);
    int   ss[2] = { s2.x, s2.y };
    int   dd[2] = { d2.x, d2.y };
    float vv[2] = { v2.x, v2.y };
    unsigned hb[2]; int pd[2], ps[2];
#pragma unroll
    for (int k = 0; k < 2; ++k) hb[k] = (unsigned)__half_as_ushort(__float2half_rn(vv[k]));
#pragma unroll
    for (int k = 0; k < 2; ++k) pd[k] = atomicAdd(&cntED[dd[k]], 1);
#pragma unroll
    for (int k = 0; k < 2; ++k) ps[k] = atomicAdd(&cntES[ss[k]], 1);
#pragma unroll
    for (int k = 0; k < 2; ++k)
      if (pd[k] < CAP_ED) listED[(size_t)dd[k] * CAP_ED + pd[k]] = ((unsigned)ss[k] << 16) | hb[k];
#pragma unroll
    for (int k = 0; k < 2; ++k)
      if (ps[k] < CAP_ES) listES[(size_t)ss[k] * CAP_ES + ps[k]] = ((unsigned)dd[k] << 16) | hb[k];
  }
}

// ---------------- state init: one wave per row (f16 stores) ----------------
__global__ __launch_bounds__(256) void init_rows_k(
    const float* __restrict__ relaxed,
    const int* __restrict__ cntID, const unsigned* __restrict__ listID,
    const int* __restrict__ cntED, const unsigned* __restrict__ listED,
    half_t* __restrict__ variables, half_t* __restrict__ constraints, half_t* __restrict__ eqcons)
{
  int widx = blockIdx.x * 4 + (threadIdx.x >> 6);
  int lane = threadIdx.x & 63;
  if (widx < VAR_N) {
    variables[((size_t)widx << 6) + lane] = (half_t)relaxed[widx];
  } else if (widx < VAR_N + CON_N) {
    int i = widx - VAR_N;
    int n = min(cntID[i], CAP_ID);
    float t = 0.0f;
    if (lane < n) {
      unsigned e = listID[(size_t)i * CAP_ID + lane];
      t = unpack_val(e) * relaxed[e >> 16];
    }
    t = wred(t);
    t = __shfl(t, 0, 64);
    constraints[((size_t)i << 6) + lane] = (half_t)t;
  } else if (widx < VAR_N + CON_N + EQ_N) {
    int i = widx - VAR_N - CON_N;
    int n = min(cntED[i], CAP_ED);
    float t = 0.0f;
    if (lane < n) {
      unsigned e = listED[(size_t)i * CAP_ED + lane];
      t = unpack_val(e) * relaxed[e >> 16];
    }
    t = wred(t);
    t = __shfl(t, 0, 64);
    eqcons[((size_t)i << 6) + lane] = (half_t)t;
  }
}

// ---------------- fused loss gathers (f16 qry reads, f16 loss writes) ----------------
__global__ __launch_bounds__(256) void gather_loss_k(
    const int* __restrict__ cntC, const unsigned* __restrict__ listC,
    const int* __restrict__ cntE, const unsigned* __restrict__ listE,
    const half_t* __restrict__ qry,
    const float* __restrict__ cv, const float* __restrict__ ecv,
    half_t* __restrict__ closs, half_t* __restrict__ eloss)
{
  constexpr int nbC = (CON_N + 3) / 4;
  int b = blockIdx.x;
  int lane = threadIdx.x & 63;
  if (b < nbC) {
    int i = b * 4 + (threadIdx.x >> 6);
    if (i >= CON_N) return;
    int n = min(cntC[i], CAP_ID);
    const uint4* lst = (const uint4*)(listC + (size_t)i * CAP_ID);
    float acc = 0.0f, ss = 0.0f;
    for (int j4 = 0; j4 * 4 < n; ++j4) {
      uint4 q = lst[j4];
#pragma unroll
      for (int k = 0; k < 4; ++k) {
        int j = j4 * 4 + k;
        if (j < n) {
          unsigned e = u4get(q, k);
          float v = unpack_val(e);
          acc = fmaf(v, (float)qry[((size_t)(e >> 16) << 6) + lane], acc);
          ss  = fmaf(v, v, ss);
        }
      }
    }
    closs[((size_t)i << 6) + lane] = (half_t)((acc - cv[i]) * rsqrtf(ss + 1e-6f));
  } else {
    int i = (b - nbC) * 4 + (threadIdx.x >> 6);
    if (i >= EQ_N) return;
    int n = min(cntE[i], CAP_ED);
    const uint4* lst = (const uint4*)(listE + (size_t)i * CAP_ED);
    float acc = 0.0f, ss = 0.0f;
    for (int j4 = 0; j4 * 4 < n; ++j4) {
      uint4 q = lst[j4];
#pragma unroll
      for (int k = 0; k < 4; ++k) {
        int j = j4 * 4 + k;
        if (j < n) {
          unsigned e = u4get(q, k);
          float v = unpack_val(e);
          acc = fmaf(v, (float)qry[((size_t)(e >> 16) << 6) + lane], acc);
          ss  = fmaf(v, v, ss);
        }
      }
    }
    float t = (ecv[i] - acc) * rsqrtf(ss + 1e-6f);
    eloss[((size_t)i << 6) + lane] = (half_t)(t * t);
  }
}

// ---------------- var-message gather (f16 reads/writes) ----------------
__global__ __launch_bounds__(256) void gather_vmsg_k(
    const int* __restrict__ cntS, const unsigned* __restrict__ listS,
    const int* __restrict__ cntES, const unsigned* __restrict__ listES,
    const half_t* __restrict__ ctmpHi, const half_t* __restrict__ etmpHi,
    half_t* __restrict__ msgs)
{
  int i = blockIdx.x * 4 + (threadIdx.x >> 6);
  if (i >= VAR_N) return;
  int lane = threadIdx.x & 63;

  float pos = 0.0f, neg = 0.0f, vss = 0.0f;
  {
    int n = min(cntS[i], CAP_IS);
    const uint4* lst = (const uint4*)(listS + (size_t)i * CAP_IS);
    for (int j4 = 0; j4 * 4 < n; ++j4) {
      uint4 q = lst[j4];
#pragma unroll
      for (int k = 0; k < 4; ++k) {
        int j = j4 * 4 + k;
        if (j < n) {
          unsigned e = u4get(q, k);
          float v = unpack_val(e);
          float c = (float)ctmpHi[((size_t)(e >> 16) << 6) + lane];
          vss = fmaf(v, v, vss);
          if (v > 0.0f) pos = fmaf(v, c, pos);
          else          neg = fmaf(-v, c, neg);
        }
      }
    }
  }
  float e2v = 0.0f;
  {
    int n = min(cntES[i], CAP_ES);
    const uint4* lst = (const uint4*)(listES + (size_t)i * CAP_ES);
    for (int j4 = 0; j4 * 4 < n; ++j4) {
      uint4 q = lst[j4];
#pragma unroll
      for (int k = 0; k < 4; ++k) {
        int j = j4 * 4 + k;
        if (j < n) {
          unsigned e = u4get(q, k);
          e2v = fmaf(unpack_val(e), (float)etmpHi[((size_t)(e >> 16) << 6) + lane], e2v);
        }
      }
    }
  }
  float ivs = rsqrtf(vss + 1e-6f);
  half_t* row = msgs + (size_t)i * 192;
  row[lane]       = (half_t)(pos * ivs);
  row[64 + lane]  = (half_t)(neg * ivs);
  row[128 + lane] = (half_t)e2v;
}

// ---------------- small kernels ----------------
__global__ __launch_bounds__(256) void sumsq_k(const float* __restrict__ x, int n, float* out)
{
  float s = 0.0f;
  for (int i = blockIdx.x * 256 + threadIdx.x; i < n; i += gridDim.x * 256) {
    float v = x[i]; s = fmaf(v, v, s);
  }
  s = wred(s);
  __shared__ float red[4];
  int lane = threadIdx.x & 63, wid = threadIdx.x >> 6;
  if (lane == 0) red[wid] = s;
  __syncthreads();
  if (threadIdx.x == 0) atomicAdd(out, red[0] + red[1] + red[2] + red[3]);
}

__global__ __launch_bounds__(256) void out_k(
    const half_t* __restrict__ H, const float* __restrict__ ssin,
    const float* __restrict__ ow2, const float* __restrict__ ob2,
    const float* __restrict__ mask, float* __restrict__ dout, int pass)
{
  int row = blockIdx.x * 4 + (threadIdx.x >> 6);
  if (row >= VAR_N) return;
  int lane = threadIdx.x & 63;
  float inv_s = rsqrtf(1e-6f + cellsum(ssin) / (float)VAR_N);
  float t = fmaxf((float)H[(size_t)row * 64 + lane] * inv_s, 0.0f) * ow2[lane];
  t = wred(t);
  if (lane == 0) {
    float ov = t + ob2[0];
    float m = mask[row];
    float sig = 1.0f / (1.0f + expf(-ov));
    dout[pass * VAR_N + row] = sig * m + ov * (1.0f - m) * 0.1f;
    if (pass == NPASS - 1) dout[3 * VAR_N + row] = ov;
  }
}

// ---------------- launch ----------------
extern "C" void kernel_launch(void* const* d_in, const int* in_sizes, int n_in,
                              void* d_out, int out_size, void* d_ws, size_t ws_size,
                              hipStream_t stream)
{
  const int*   isrc = (const int*)  d_in[0];
  const int*   idst = (const int*)  d_in[1];
  const float* ival = (const float*)d_in[2];
  const int*   esrc = (const int*)  d_in[3];
  const int*   edst = (const int*)  d_in[4];
  const float* evalv= (const float*)d_in[5];
  const float* cv   = (const float*)d_in[6];
  const float* ecv  = (const float*)d_in[7];
  const float* relaxed = (const float*)d_in[8];
  const float* obj  = (const float*)d_in[9];
  const float* mask = (const float*)d_in[10];
  const float* noise= (const float*)d_in[11];
  const float* q_w1 = (const float*)d_in[12];
  const float* q_b1 = (const float*)d_in[13];
  const float* q_w2 = (const float*)d_in[14];
  const float* q_b2 = (const float*)d_in[15];
  const float* cu_w1= (const float*)d_in[16];
  const float* cu_b1= (const float*)d_in[17];
  const float* cu_w2= (const float*)d_in[18];
  const float* cu_b2= (const float*)d_in[19];
  const float* ec_w1= (const float*)d_in[20];
  const float* ec_b1= (const float*)d_in[21];
  const float* ec_w2= (const float*)d_in[22];
  const float* ec_b2= (const float*)d_in[23];
  const float* vu_w1= (const float*)d_in[24];
  const float* vu_b1= (const float*)d_in[25];
  const float* vu_w2= (const float*)d_in[26];
  const float* vu_b2= (const float*)d_in[27];
  const float* o_w1 = (const float*)d_in[28];
  const float* o_b1 = (const float*)d_in[29];
  const float* o_w2 = (const float*)d_in[30];
  const float* o_b2 = (const float*)d_in[31];
  float* dout = (float*)d_out;
  float* w = (float*)d_ws;

  size_t off = 0;
  auto A = [&](size_t n){ size_t o = off; off += (n + 63) & ~(size_t)63; return o; };
  // f16 buffers allocated in float-units (half wasted; harmless)
  const size_t oVarA  = A((size_t)VAR_N * 64);
  const size_t oVarB  = A((size_t)VAR_N * 64);
  const size_t oCons  = A((size_t)CON_N * 64);
  const size_t oEqc   = A((size_t)EQ_N  * 64);
  const size_t oQry   = A((size_t)VAR_N * 64);
  const size_t oH     = A((size_t)VAR_N * 64);
  const size_t oHE    = A((size_t)EQ_N  * 64);
  const size_t oCtmp  = A((size_t)CON_N * 64);
  const size_t oEtmp  = A((size_t)EQ_N  * 64);
  const size_t oCloss = A((size_t)CON_N * 64);
  const size_t oEloss = A((size_t)EQ_N  * 64);
  const size_t oMsgs  = A((size_t)VAR_N * 192);
  const size_t oScal  = A(2048);    // [objss | 15 ss-slots x 128]
  const size_t oWT    = A(32768);   // 65536 halves
  const size_t oCntID = A(CON_N);
  const size_t oCntIS = A(VAR_N);
  const size_t oCntED = A(EQ_N);
  const size_t oCntES = A(VAR_N);
  const size_t oListID = A((size_t)CON_N * CAP_ID);
  const size_t oListIS = A((size_t)VAR_N * CAP_IS);
  const size_t oListED = A((size_t)EQ_N  * CAP_ED);
  const size_t oListES = A((size_t)VAR_N * CAP_ES);

  float* scal = w + oScal;
  half_t* wtBase = (half_t*)(w + oWT);
  int*  cntID = (int*)(w + oCntID);
  int*  cntIS = (int*)(w + oCntIS);
  int*  cntED = (int*)(w + oCntED);
  int*  cntES = (int*)(w + oCntES);
  unsigned* listID = (unsigned*)(w + oListID);
  unsigned* listIS = (unsigned*)(w + oListIS);
  unsigned* listED = (unsigned*)(w + oListED);
  unsigned* listES = (unsigned*)(w + oListES);

  half_t* hVarA  = (half_t*)(w + oVarA);
  half_t* hVarB  = (half_t*)(w + oVarB);
  half_t* hCons  = (half_t*)(w + oCons);
  half_t* hEqc   = (half_t*)(w + oEqc);
  half_t* hQry   = (half_t*)(w + oQry);
  half_t* hH     = (half_t*)(w + oH);
  half_t* hHE    = (half_t*)(w + oHE);
  half_t* hCtmp  = (half_t*)(w + oCtmp);
  half_t* hEtmp  = (half_t*)(w + oEtmp);
  half_t* hCloss = (half_t*)(w + oCloss);
  half_t* hEloss = (half_t*)(w + oEloss);
  half_t* hMsgs  = (half_t*)(w + oMsgs);

  // WT offsets (halves), layout [C][K] per matrix
  const int bQ1 = 0,      bQ2 = 4096,  bCU1 = 8192,  bCU2 = 16384, bEC1 = 24576;
  const int bEC2 = 32768, bVU1 = 40960, bVU2 = 57344, bO1 = 61440;

  hipMemsetAsync((void*)(w + oScal), 0, 2048 * 4, stream);
  hipMemsetAsync((void*)(w + oCntID), 0, (oListID - oCntID) * 4, stream);

  {
    PrepArgs pa;
    const float* srcs[9] = { q_w1, q_w2, cu_w1, cu_w2, ec_w1, ec_w2, vu_w1, vu_w2, o_w1 };
    int Ks[9]   = { 64, 64, 128, 64, 128, 64, 256, 64, 64 };
    int Cs[9]   = { 64, 64, 64, 128, 64, 128, 64, 64, 64 };
    int bases[9]= { bQ1, bQ2, bCU1, bCU2, bEC1, bEC2, bVU1, bVU2, bO1 };
    for (int i = 0; i < 9; ++i) {
      pa.src[i] = srcs[i]; pa.K[i] = Ks[i]; pa.C[i] = Cs[i];
      pa.base[i] = bases[i]; pa.end[i] = bases[i] + Ks[i] * Cs[i];
    }
    prep_wt_k<<<(65536 + 255) / 256, 256, 0, stream>>>(pa, wtBase);
  }

  build_all_k<<<(QI2 + QE2 + 255) / 256, 256, 0, stream>>>(
      isrc, idst, ival, esrc, edst, evalv,
      cntID, listID, cntIS, listIS, cntED, listED, cntES, listES);
  sumsq_k<<<64, 256, 0, stream>>>(obj, VAR_N, scal);
  init_rows_k<<<(VAR_N + CON_N + EQ_N + 3) / 4, 256, 0, stream>>>(
      relaxed, cntID, listID, cntED, listED, hVarA, hCons, hEqc);

  half_t* varCur = hVarA;
  half_t* varNxt = hVarB;

  GemmSide Z = {};
  const int NBV = 768;
  const int NBC = 640, NBE = 128;

  for (int p = 0; p < NPASS; ++p) {
    float* ssq0 = scal + 16 + (size_t)(p * 5 + 0) * 128;
    float* ssq1 = scal + 16 + (size_t)(p * 5 + 1) * 128;
    float* ssq2 = scal + 16 + (size_t)(p * 5 + 2) * 128;
    float* ssq3 = scal + 16 + (size_t)(p * 5 + 3) * 128;
    float* ssq4 = scal + 16 + (size_t)(p * 5 + 4) * 128;

    // q-MLP layer 1: H = [varCur|noise] @ q_w1 + b1, ss -> ssq0
    {
      GemmSide S = { varCur, nullptr, wtBase + bQ1, q_w1, q_b1, hH, nullptr, nullptr,
                     nullptr, ssq0, 1.0f,
                     noise + (size_t)p * VAR_N * 4, nullptr, nullptr, VAR_N, NBV };
      mlp_gemm<64, 64, 0, 1, false, true, 0><<<NBV, 256, 0, stream>>>(S, Z);
    }
    // q-MLP layer 2: qry = relu-norm(H) @ q_w2 + b2 + 0.5*mask
    {
      GemmSide S = { hH, nullptr, wtBase + bQ2, q_w2, q_b2, hQry, nullptr, mask,
                     ssq0, nullptr, (float)VAR_N,
                     nullptr, nullptr, nullptr, VAR_N, NBV };
      mlp_gemm<64, 64, 0, 0, true, false, 1><<<NBV, 256, 0, stream>>>(S, Z);
    }
    // fused loss gathers
    gather_loss_k<<<(CON_N + 3) / 4 + (EQ_N + 3) / 4, 256, 0, stream>>>(
        cntID, listID, cntED, listED, hQry, cv, ecv, hCloss, hEloss);
    // cu/ec MLP layer 1 (batched)
    {
      GemmSide Sa = { hCons, hCloss, wtBase + bCU1, cu_w1, cu_b1, hH, nullptr, nullptr,
                      nullptr, ssq1, 1.0f, nullptr, nullptr, nullptr, CON_N, NBC };
      GemmSide Sb = { hEqc, hEloss, wtBase + bEC1, ec_w1, ec_b1, hHE, nullptr, nullptr,
                      nullptr, ssq2, 1.0f, nullptr, nullptr, nullptr, EQ_N, NBE };
      mlp_gemm<128, 64, 1, 0, false, true, 0><<<NBC + NBE, 256, 0, stream>>>(Sa, Sb);
    }
    // cu/ec MLP layer 2 (batched, fused state update)
    {
      GemmSide Sa = { hH, nullptr, wtBase + bCU2, cu_w2, cu_b2, hCtmp, hCons, nullptr,
                      ssq1, nullptr, (float)CON_N, nullptr, nullptr, nullptr, CON_N, NBC };
      GemmSide Sb = { hHE, nullptr, wtBase + bEC2, ec_w2, ec_b2, hEtmp, hEqc, nullptr,
                      ssq2, nullptr, (float)EQ_N, nullptr, nullptr, nullptr, EQ_N, NBE };
      mlp_gemm<64, 128, 0, 0, true, false, 3><<<NBC + NBE, 256, 0, stream>>>(Sa, Sb);
    }
    // var message gather
    gather_vmsg_k<<<(VAR_N + 3) / 4, 256, 0, stream>>>(
        cntIS, listIS, cntES, listES, hCtmp, hEtmp, hMsgs);
    // vu layer 1: H = [varCur|msgs|objn|mask] @ vu_w1, ss -> ssq3
    {
      GemmSide S = { varCur, hMsgs, wtBase + bVU1, vu_w1, vu_b1, hH, nullptr, nullptr,
                     nullptr, ssq3, 1.0f, obj, mask, scal, VAR_N, NBV };
      mlp_gemm<256, 64, 1, 2, false, true, 0><<<NBV, 256, 0, stream>>>(S, Z);
    }
    // vu layer 2: varNxt = relu-norm(H)@vu_w2 + b2 + 0.5*varCur
    {
      GemmSide S = { hH, nullptr, wtBase + bVU2, vu_w2, vu_b2, varNxt, varCur, nullptr,
                     ssq3, nullptr, (float)VAR_N, nullptr, nullptr, nullptr, VAR_N, NBV };
      mlp_gemm<64, 64, 0, 0, true, false, 2><<<NBV, 256, 0, stream>>>(S, Z);
    }
    // o layer 1: H = varNxt @ o_w1 + b1, ss -> ssq4
    {
      GemmSide S = { varNxt, nullptr, wtBase + bO1, o_w1, o_b1, hH, nullptr, nullptr,
                     nullptr, ssq4, 1.0f, nullptr, nullptr, nullptr, VAR_N, NBV };
      mlp_gemm<64, 64, 0, 0, false, true, 0><<<NBV, 256, 0, stream>>>(S, Z);
    }
    out_k<<<(VAR_N + 3) / 4, 256, 0, stream>>>(hH, ssq4, o_w2, o_b2, mask, dout, p);

    half_t* t = varCur; varCur = varNxt; varNxt = t;
  }
}